// Round 8
// baseline (169.742 us; speedup 1.0000x reference)
//
#include <hip/hip_runtime.h>
#include <hip/hip_bf16.h>
#include <math.h>
#include <cstdint>
#include <cstddef>

typedef __bf16 bf16x8 __attribute__((ext_vector_type(8)));
typedef float  f32x4  __attribute__((ext_vector_type(4)));
typedef float  f32x16 __attribute__((ext_vector_type(16)));

#define GLOAD16(g, l) __builtin_amdgcn_global_load_lds( \
    (const __attribute__((address_space(1))) void*)(g),  \
    (__attribute__((address_space(3))) void*)(l), 16, 0, 0)

__device__ __forceinline__ unsigned short f2bf(float f) {
    union { float f; unsigned u; } v; v.f = f;
    unsigned u = v.u;
    u += 0x7fffu + ((u >> 16) & 1u);          // round-to-nearest-even
    return (unsigned short)(u >> 16);
}

__device__ __forceinline__ unsigned pack_bf16x2(float a, float b) {
    __hip_bfloat162 h = __float22bfloat162_rn(make_float2(a, b));
    return *reinterpret_cast<unsigned*>(&h);   // v_cvt_pk_bf16_f32
}

__device__ __forceinline__ f32x16 mfma32(bf16x8 a, bf16x8 b, f32x16 c) {
    return __builtin_amdgcn_mfma_f32_32x32x16_bf16(a, b, c, 0, 0, 0);
}

// ---- fused fp32 -> bf16 converts (x | qkv_w [Q rows pre-scaled] | proj_w) ----
__global__ __launch_bounds__(256) void cvt_all(
    const float* __restrict__ x,
    const float* __restrict__ qkvw,
    const float* __restrict__ projw,
    unsigned short* __restrict__ xb,
    unsigned short* __restrict__ wqkv,
    unsigned short* __restrict__ wproj)
{
    const int N1 = 4096 * 768;          // x
    const int N2 = 2304 * 768;          // qkv_w
    const int SC = 768 * 768;           // Q rows of qkv_w (scaled)
    const float C2 = 0.18033688011112042f;   // 0.125 * log2(e)
    int i = ((int)blockIdx.x * 256 + (int)threadIdx.x) * 4;

    const float* src;
    unsigned short* dst;
    int j;
    bool sc = false;
    if (i < N1)           { src = x;     dst = xb;    j = i; }
    else if (i < N1 + N2) { j = i - N1;  src = qkvw;  dst = wqkv;  sc = (j < SC); }
    else                  { j = i - N1 - N2; src = projw; dst = wproj; }

    float4 v = *reinterpret_cast<const float4*>(src + j);
    if (sc) { v.x *= C2; v.y *= C2; v.z *= C2; v.w *= C2; }
    uint2 pk;
    pk.x = pack_bf16x2(v.x, v.y);
    pk.y = pack_bf16x2(v.z, v.w);
    *reinterpret_cast<uint2*>(dst + j) = pk;
}

// -------- bf16 GEMM, C = A * B^T, 2-phase double-buffered staging ----------
// MODE 1: fp32 out + bias. MODE 2: qkv split (Q,K -> qk[.][1536]; V -> vT^T).
template <int MODE, int MROWS, int NF>
__global__ __launch_bounds__(256) void gemm_bt(
    const unsigned short* __restrict__ A,
    const unsigned short* __restrict__ B,
    unsigned short* __restrict__ Cb,
    unsigned short* __restrict__ Vt,
    float* __restrict__ Cf,
    const float* __restrict__ bias,
    int M, int N, int K)
{
    constexpr int MI = MROWS / 32;
    __shared__ __align__(16) unsigned short Al[2][MROWS * 64];
    __shared__ __align__(16) unsigned short Bl[2][NF * 32 * 64];
    const int bm   = blockIdx.x * MROWS;
    const int bn   = blockIdx.y * (NF * 32);
    const int tid  = (int)threadIdx.x;
    const int wave = tid >> 6;
    const int lane = tid & 63;
    const int wr   = wave >> 1;
    const int wc   = wave & 1;
    const int q    = lane & 15;
    const int g4   = (lane >> 4) * 4;

    f32x4 acc[MI][NF] = {};

    const int srow = lane >> 3;
    const int scol = (lane & 7) * 8;

    auto stage = [&](int buf, int k0) {
#pragma unroll
        for (int i = 0; i < MI; ++i) {
            const int chunk = wave * MI + i;
            GLOAD16(A + (size_t)(bm + chunk * 8 + srow) * K + (k0 + scol),
                    &Al[buf][chunk * 512]);
        }
#pragma unroll
        for (int i = 0; i < NF; ++i) {
            const int chunk = wave * NF + i;
            GLOAD16(B + (size_t)(bn + chunk * 8 + srow) * K + (k0 + scol),
                    &Bl[buf][chunk * 512]);
        }
    };

    stage(0, 0);
    __syncthreads();

    const int nt = K / 64;
    int buf = 0;
    for (int t = 0; t < nt; ++t) {
        if (t + 1 < nt) stage(buf ^ 1, (t + 1) * 64);   // issue before compute
#pragma unroll
        for (int kk = 0; kk < 2; ++kk) {
            const int ko = kk * 32 + (lane >> 4) * 8;
            bf16x8 af[MI], bf[NF];
#pragma unroll
            for (int mi = 0; mi < MI; ++mi)
                af[mi] = *(const bf16x8*)&Al[buf][(wr * (MROWS / 2) + mi * 16 + q) * 64 + ko];
#pragma unroll
            for (int ni = 0; ni < NF; ++ni)
                bf[ni] = *(const bf16x8*)&Bl[buf][(wc * 16 * NF + ni * 16 + q) * 64 + ko];
#pragma unroll
            for (int mi = 0; mi < MI; ++mi)
#pragma unroll
                for (int ni = 0; ni < NF; ++ni)
                    acc[mi][ni] = __builtin_amdgcn_mfma_f32_16x16x32_bf16(
                        af[mi], bf[ni], acc[mi][ni], 0, 0, 0);
        }
        __syncthreads();             // drains this iter's stage + closes reads
        buf ^= 1;
    }

#pragma unroll
    for (int mi = 0; mi < MI; ++mi) {
        const int row0 = bm + wr * (MROWS / 2) + mi * 16 + g4;
        if constexpr (MODE == 1) {
#pragma unroll
            for (int ni = 0; ni < NF; ++ni) {
                const int col = bn + wc * 16 * NF + ni * 16 + q;
#pragma unroll
                for (int r = 0; r < 4; ++r)
                    Cf[(size_t)(row0 + r) * N + col] = acc[mi][ni][r] + bias[col];
            }
        } else {
            if (bn < 1536) {
#pragma unroll
                for (int ni = 0; ni < NF; ++ni) {
                    const int col = bn + wc * 16 * NF + ni * 16 + q;
#pragma unroll
                    for (int r = 0; r < 4; ++r)
                        Cb[(size_t)(row0 + r) * 1536 + col] = f2bf(acc[mi][ni][r]);
                }
            } else {
                const int b  = row0 >> 11;
                const int np = row0 & 2047;
#pragma unroll
                for (int ni = 0; ni < NF; ++ni) {
                    const int vcol = bn + wc * 16 * NF + ni * 16 + q - 1536;
                    const int hv = vcol >> 6, d = vcol & 63;
                    uint2 w;
                    w.x = pack_bf16x2(acc[mi][ni][0], acc[mi][ni][1]);
                    w.y = pack_bf16x2(acc[mi][ni][2], acc[mi][ni][3]);
                    *reinterpret_cast<uint2*>(
                        &Vt[((size_t)(b * 12 + hv) * 64 + d) * 2048 + np]) = w;
                }
            }
        }
    }
}

// ------ fused flash attention: 32x32 MFMA, kv-split 32/wave, P in regs -----
// qk: [B*N][1536] bf16 (Q pre-scaled, cols 0..768; K cols 768..1536)
// vT: [B*H*64][2048] bf16 ; out: [B*N][768] bf16
// Block: 64 q-cols x full kv; KVBLK=128/iter (wave w owns kv rows 32w..32w+32).
__global__ __launch_bounds__(256, 2) void attn_fwd(
    const unsigned short* __restrict__ qk,
    const unsigned short* __restrict__ vT,
    const int* __restrict__ mask,
    unsigned short* __restrict__ out)
{
    const int NN = 2048, H = 12;
    const int bh = (int)blockIdx.y;
    const int b  = bh / H, h = bh % H;
    const int q0 = (int)blockIdx.x * 64;
    const int tid = (int)threadIdx.x, wave = tid >> 6, lane = tid & 63;
    const int ql = lane & 31;          // q-col / kv-row / d-row within 32-group
    const int hi = lane >> 5;

    // LDS: Kl[2][128*64] (32768 B) | Vl[64][130] (16640 B)  => 49408 B
    __shared__ __align__(16) unsigned short LDS[24704];
    unsigned short* Kl = LDS;            // 2 bufs of 8192 elems
    unsigned short* Vl = LDS + 16384;    // 64 rows, pitch 130 elems

    // wave-local mask vote: all 2048 entries nonzero?
    bool allone;
    {
        const int* mrow = mask + b * NN + lane * 32;
        unsigned mv = 0xFFFFFFFFu;
#pragma unroll
        for (int i = 0; i < 8; ++i) {
            int4 m = *reinterpret_cast<const int4*>(mrow + i * 4);
            mv = min(mv, min(min((unsigned)m.x, (unsigned)m.y),
                             min((unsigned)m.z, (unsigned)m.w)));
        }
        allone = __all(mv != 0u);
    }

    // Q B-frags (pre-scaled): qf[qg][kg]: col=q0+32qg+ql, k=d=16kg+8hi+j
    bf16x8 qf[2][4];
#pragma unroll
    for (int qg = 0; qg < 2; ++qg)
#pragma unroll
        for (int kg = 0; kg < 4; ++kg)
            qf[qg][kg] = *reinterpret_cast<const bf16x8*>(
                &qk[(size_t)(b * NN + q0 + 32 * qg + ql) * 1536 + h * 64 + 16 * kg + 8 * hi]);

    // K staging: wave-private rows 32w..32w+32, gload_lds, inverse-swizzled src
    const char* kgp = (const char*)(qk + (size_t)(b * NN + 32 * wave + (lane >> 3)) * 1536
                                    + 768 + h * 64 + ((lane & 7) ^ (lane >> 3)) * 8);
    // V staging (reg path, d-major): wave stages d-rows 16w..16w+16
    const unsigned short* vgp = vT + (size_t)(bh * 64 + 16 * wave + (lane >> 2)) * 2048
                                + (lane & 3) * 32;
    const int vdst = (16 * wave + (lane >> 2)) * 130 + (lane & 3) * 32;

    auto stageK = [&](int buf) {
#pragma unroll
        for (int c = 0; c < 4; ++c)
            GLOAD16(kgp + (size_t)c * (8 * 1536 * 2),
                    &Kl[buf * 8192 + (32 * wave + 8 * c) * 64]);
        kgp += (size_t)128 * 1536 * 2;
    };
    uint4 vr0, vr1, vr2, vr3;
    auto loadV = [&]() {
        vr0 = *reinterpret_cast<const uint4*>(vgp);
        vr1 = *reinterpret_cast<const uint4*>(vgp + 8);
        vr2 = *reinterpret_cast<const uint4*>(vgp + 16);
        vr3 = *reinterpret_cast<const uint4*>(vgp + 24);
        vgp += 128;
    };
    auto writeV = [&]() {
        *reinterpret_cast<uint4*>(&Vl[vdst])      = vr0;
        *reinterpret_cast<uint4*>(&Vl[vdst + 8])  = vr1;
        *reinterpret_cast<uint4*>(&Vl[vdst + 16]) = vr2;
        *reinterpret_cast<uint4*>(&Vl[vdst + 24]) = vr3;
    };

    f32x16 oacc[2][2] = {};          // [dgrp][qg]
    float l0 = 0.f, l1 = 0.f;

    // prologue: V(0) regs + K(0) in flight; write V(0); K(0) stays counted
    loadV(); stageK(0);
    asm volatile("s_waitcnt vmcnt(4)" ::: "memory");
    writeV();
    asm volatile("s_waitcnt lgkmcnt(0)\n\ts_barrier" ::: "memory");

    int cur = 0;
    for (int it = 0; it < 16; ++it) {
        if (it < 15) { loadV(); stageK(cur ^ 1); }   // V(it+1) regs, K(it+1) lds

        // wait K(it) resident (8 newest = this iter's V+K stay in flight)
        if (it < 15) asm volatile("s_waitcnt vmcnt(8)" ::: "memory");
        else         asm volatile("s_waitcnt vmcnt(0)" ::: "memory");

        // S^T[own 32 kv][64 q] = K * Q^T (exp2 units)
        f32x16 s[2] = {};
        __builtin_amdgcn_s_setprio(1);
#pragma unroll
        for (int kg = 0; kg < 4; ++kg) {
            bf16x8 kf = *reinterpret_cast<const bf16x8*>(
                &Kl[cur * 8192 + (32 * wave + ql) * 64 + (((2 * kg + hi) ^ (ql & 7)) * 8)]);
            s[0] = mfma32(kf, qf[0][kg], s[0]);
            s[1] = mfma32(kf, qf[1][kg], s[1]);
        }
        __builtin_amdgcn_s_setprio(0);

        if (!allone) {               // cold path: kv = it*128 + 32w + (r&3)+8(r>>2)+4hi
            const int* mp = &mask[b * NN + it * 128 + 32 * wave + 4 * hi];
#pragma unroll
            for (int r4 = 0; r4 < 4; ++r4) {
                int4 m = *reinterpret_cast<const int4*>(mp + 8 * r4);
                if (m.x == 0) { s[0][r4 * 4 + 0] = -INFINITY; s[1][r4 * 4 + 0] = -INFINITY; }
                if (m.y == 0) { s[0][r4 * 4 + 1] = -INFINITY; s[1][r4 * 4 + 1] = -INFINITY; }
                if (m.z == 0) { s[0][r4 * 4 + 2] = -INFINITY; s[1][r4 * 4 + 2] = -INFINITY; }
                if (m.w == 0) { s[0][r4 * 4 + 3] = -INFINITY; s[1][r4 * 4 + 3] = -INFINITY; }
            }
        }

        // p = exp2(s); l partials; build PV B-frags in registers (shfl across hi)
        bf16x8 pb[2][2];
#pragma unroll
        for (int qg = 0; qg < 2; ++qg) {
            float p[16];
#pragma unroll
            for (int i = 0; i < 16; ++i)
                p[i] = __builtin_amdgcn_exp2f(s[qg][i]);
            float ls = (((p[0] + p[1]) + (p[2] + p[3])) + ((p[4] + p[5]) + (p[6] + p[7])))
                     + (((p[8] + p[9]) + (p[10] + p[11])) + ((p[12] + p[13]) + (p[14] + p[15])));
            if (qg == 0) l0 += ls; else l1 += ls;
#pragma unroll
            for (int m = 0; m < 2; ++m) {
                unsigned a0 = pack_bf16x2(p[8 * m + 0], p[8 * m + 1]);
                unsigned a1 = pack_bf16x2(p[8 * m + 2], p[8 * m + 3]);
                unsigned b0 = pack_bf16x2(p[8 * m + 4], p[8 * m + 5]);
                unsigned b1 = pack_bf16x2(p[8 * m + 6], p[8 * m + 7]);
                unsigned sa0 = (unsigned)__shfl_xor((int)a0, 32);
                unsigned sa1 = (unsigned)__shfl_xor((int)a1, 32);
                unsigned sb0 = (unsigned)__shfl_xor((int)b0, 32);
                unsigned sb1 = (unsigned)__shfl_xor((int)b1, 32);
                uint4 w;
                w.x = hi ? sb0 : a0;
                w.y = hi ? sb1 : a1;
                w.z = hi ? b0 : sa0;
                w.w = hi ? b1 : sa1;
                pb[qg][m] = __builtin_bit_cast(bf16x8, w);
            }
        }

        // O^T[64 d][64 q] partial += V^T * P^T  (A = V^T rows d, k = own kv)
        __builtin_amdgcn_s_setprio(1);
#pragma unroll
        for (int dg = 0; dg < 2; ++dg)
#pragma unroll
            for (int m = 0; m < 2; ++m) {
                bf16x8 va = *reinterpret_cast<const bf16x8*>(
                    &Vl[(32 * dg + ql) * 130 + 32 * wave + 16 * m + 8 * hi]);
                oacc[dg][0] = mfma32(va, pb[0][m], oacc[dg][0]);
                oacc[dg][1] = mfma32(va, pb[1][m], oacc[dg][1]);
            }
        __builtin_amdgcn_s_setprio(0);

        // rotate V: all PV reads done -> write V(it+1) -> visible
        asm volatile("s_barrier" ::: "memory");
        if (it < 15) {
            asm volatile("s_waitcnt vmcnt(4)" ::: "memory");   // V regs ready; K in flight
            writeV();
        }
        asm volatile("s_waitcnt lgkmcnt(0)\n\ts_barrier" ::: "memory");
        cur ^= 1;
    }

    // ---- epilogue: reduce l and O across waves ----
    l0 += __shfl_xor(l0, 32);
    l1 += __shfl_xor(l1, 32);

    float* sc = (float*)LDS;                 // 8192 f32 scratch (K area)
    float* lb = (float*)(LDS + 16384);       // 256 f32 (V area)
    if (hi == 0) { lb[wave * 64 + ql] = l0; lb[wave * 64 + 32 + ql] = l1; }

    if (wave & 1) {                          // waves 1,3 dump full O (16 KB each)
        float* dst = sc + (wave >> 1) * 4096;
#pragma unroll
        for (int dg = 0; dg < 2; ++dg)
#pragma unroll
            for (int qg = 0; qg < 2; ++qg)
#pragma unroll
                for (int r4 = 0; r4 < 4; ++r4) {
                    f32x4 t = { oacc[dg][qg][r4 * 4 + 0], oacc[dg][qg][r4 * 4 + 1],
                                oacc[dg][qg][r4 * 4 + 2], oacc[dg][qg][r4 * 4 + 3] };
                    *reinterpret_cast<f32x4*>(&dst[(dg * 2 + qg) * 1024 + r4 * 256 + lane * 4]) = t;
                }
    }
    __syncthreads();
    if (!(wave & 1)) {                       // waves 0,2 absorb partners
        float* srcp = sc + (wave >> 1) * 4096;
#pragma unroll
        for (int dg = 0; dg < 2; ++dg)
#pragma unroll
            for (int qg = 0; qg < 2; ++qg)
#pragma unroll
                for (int r4 = 0; r4 < 4; ++r4) {
                    f32x4 t = *reinterpret_cast<f32x4*>(
                        &srcp[(dg * 2 + qg) * 1024 + r4 * 256 + lane * 4]);
                    oacc[dg][qg][r4 * 4 + 0] += t[0];
                    oacc[dg][qg][r4 * 4 + 1] += t[1];
                    oacc[dg][qg][r4 * 4 + 2] += t[2];
                    oacc[dg][qg][r4 * 4 + 3] += t[3];
                }
    }
    __syncthreads();
    if (wave == 0 || wave == 2) {            // exchange d-halves
        const int dgd = (wave == 0) ? 1 : 0;
        float* dst = sc + ((wave == 0) ? 0 : 2048);
#pragma unroll
        for (int qg = 0; qg < 2; ++qg)
#pragma unroll
            for (int r4 = 0; r4 < 4; ++r4) {
                f32x4 t = { oacc[dgd][qg][r4 * 4 + 0], oacc[dgd][qg][r4 * 4 + 1],
                            oacc[dgd][qg][r4 * 4 + 2], oacc[dgd][qg][r4 * 4 + 3] };
                *reinterpret_cast<f32x4*>(&dst[qg * 1024 + r4 * 256 + lane * 4]) = t;
            }
    }
    __syncthreads();
    if (wave == 0 || wave == 2) {            // finalize + store disjoint halves
        const int dg = (wave == 0) ? 0 : 1;
        float* srcp = sc + ((wave == 0) ? 2048 : 0);
        const float inv0 = 1.0f / (lb[ql] + lb[64 + ql] + lb[128 + ql] + lb[192 + ql]);
        const float inv1 = 1.0f / (lb[32 + ql] + lb[96 + ql] + lb[160 + ql] + lb[224 + ql]);
#pragma unroll
        for (int qg = 0; qg < 2; ++qg) {
            const float inv = qg ? inv1 : inv0;
            const size_t orow = (size_t)(b * NN + q0 + 32 * qg + ql) * 768 + h * 64;
#pragma unroll
            for (int r4 = 0; r4 < 4; ++r4) {
                f32x4 t = *reinterpret_cast<f32x4*>(&srcp[qg * 1024 + r4 * 256 + lane * 4]);
                float o0 = (oacc[dg][qg][r4 * 4 + 0] + t[0]) * inv;
                float o1 = (oacc[dg][qg][r4 * 4 + 1] + t[1]) * inv;
                float o2 = (oacc[dg][qg][r4 * 4 + 2] + t[2]) * inv;
                float o3 = (oacc[dg][qg][r4 * 4 + 3] + t[3]) * inv;
                uint2 ow;
                ow.x = pack_bf16x2(o0, o1);
                ow.y = pack_bf16x2(o2, o3);
                *reinterpret_cast<uint2*>(&out[orow + 32 * dg + 8 * r4 + 4 * hi]) = ow;
            }
        }
    }
}

// ---------------- host launch ----------------
extern "C" void kernel_launch(void* const* d_in, const int* in_sizes, int n_in,
                              void* d_out, int out_size, void* d_ws, size_t ws_size,
                              hipStream_t stream)
{
    const float* x      = (const float*)d_in[0];
    const int*   mask   = (const int*)d_in[1];
    const float* qkv_w  = (const float*)d_in[2];
    const float* proj_w = (const float*)d_in[3];
    const float* proj_b = (const float*)d_in[4];
    float* out = (float*)d_out;

    const int BN = 2 * 2048;
    const int C  = 768;
    const int C3 = 2304;

    char* w = (char*)d_ws;
    unsigned short* xb    = (unsigned short*)w; w += (size_t)BN * C    * 2;
    unsigned short* wqkv  = (unsigned short*)w; w += (size_t)C3 * C    * 2;
    unsigned short* wproj = (unsigned short*)w; w += (size_t)C  * C    * 2;
    unsigned short* qk    = (unsigned short*)w; w += (size_t)BN * 1536 * 2;
    unsigned short* vT    = (unsigned short*)w; w += (size_t)24 * 64 * 2048 * 2;
    unsigned short* ao    = (unsigned short*)w;

    // fused converts (Q weight rows pre-scaled by 0.125*log2e)
    {
        const int total = (BN * C + C3 * C + C * C) / 4;
        cvt_all<<<total / 256, 256, 0, stream>>>(x, qkv_w, proj_w, xb, wqkv, wproj);
    }

    // qkv GEMM with split epilogue: Q,K -> qk[.][1536]; V -> vT (transposed)
    gemm_bt<2, 128, 4><<<dim3(BN / 128, C3 / 128), 256, 0, stream>>>(
        xb, wqkv, qk, vT, nullptr, nullptr, BN, C3, C);

    attn_fwd<<<dim3(2048 / 64, 24), 256, 0, stream>>>(qk, vT, mask, ao);

    // out = ao @ proj_w^T + b (fp32), 64x64 tiles -> 768 blocks (3/CU balanced)
    gemm_bt<1, 64, 2><<<dim3(BN / 64, C / 64), 256, 0, stream>>>(
        ao, wproj, nullptr, nullptr, out, proj_b, BN, C, C);
}

// Round 9
// 110.027 us; speedup vs baseline: 1.5427x; 1.5427x over previous
//
#include <hip/hip_runtime.h>
#include <hip/hip_bf16.h>
#include <math.h>
#include <cstdint>
#include <cstddef>

typedef __bf16 bf16x8 __attribute__((ext_vector_type(8)));
typedef __bf16 bf16x4 __attribute__((ext_vector_type(4)));
typedef short  s16x4  __attribute__((ext_vector_type(4)));
typedef float  f32x4  __attribute__((ext_vector_type(4)));

#define GLOAD16(g, l) __builtin_amdgcn_global_load_lds( \
    (const __attribute__((address_space(1))) void*)(g),  \
    (__attribute__((address_space(3))) void*)(l), 16, 0, 0)

__device__ __forceinline__ unsigned short f2bf(float f) {
    union { float f; unsigned u; } v; v.f = f;
    unsigned u = v.u;
    u += 0x7fffu + ((u >> 16) & 1u);          // round-to-nearest-even
    return (unsigned short)(u >> 16);
}

__device__ __forceinline__ unsigned pack_bf16x2(float a, float b) {
    __hip_bfloat162 h = __float22bfloat162_rn(make_float2(a, b));
    return *reinterpret_cast<unsigned*>(&h);   // v_cvt_pk_bf16_f32
}

// 16x16x16 bf16 MFMA (2-VGPR A/B operands, kv as k-dim)
__device__ __forceinline__ f32x4 mfma16(bf16x4 a, bf16x4 b, f32x4 c) {
#if __has_builtin(__builtin_amdgcn_mfma_f32_16x16x16_bf16)
    return __builtin_amdgcn_mfma_f32_16x16x16_bf16(a, b, c, 0, 0, 0);
#elif __has_builtin(__builtin_amdgcn_mfma_f32_16x16x16bf16_1k)
    return __builtin_amdgcn_mfma_f32_16x16x16bf16_1k(
        __builtin_bit_cast(s16x4, a), __builtin_bit_cast(s16x4, b), c, 0, 0, 0);
#else
    asm volatile("v_mfma_f32_16x16x16_bf16 %0, %1, %2, %0"
                 : "+v"(c) : "v"(a), "v"(b));
    return c;
#endif
}

// ---- fused fp32 -> bf16 converts (x | qkv_w [Q rows pre-scaled] | proj_w) ----
__global__ __launch_bounds__(256) void cvt_all(
    const float* __restrict__ x,
    const float* __restrict__ qkvw,
    const float* __restrict__ projw,
    unsigned short* __restrict__ xb,
    unsigned short* __restrict__ wqkv,
    unsigned short* __restrict__ wproj)
{
    const int N1 = 4096 * 768;          // x
    const int N2 = 2304 * 768;          // qkv_w
    const int SC = 768 * 768;           // Q rows of qkv_w (scaled)
    const float C2 = 0.18033688011112042f;   // 0.125 * log2(e)
    int i = ((int)blockIdx.x * 256 + (int)threadIdx.x) * 4;

    const float* src;
    unsigned short* dst;
    int j;
    bool sc = false;
    if (i < N1)           { src = x;     dst = xb;    j = i; }
    else if (i < N1 + N2) { j = i - N1;  src = qkvw;  dst = wqkv;  sc = (j < SC); }
    else                  { j = i - N1 - N2; src = projw; dst = wproj; }

    float4 v = *reinterpret_cast<const float4*>(src + j);
    if (sc) { v.x *= C2; v.y *= C2; v.z *= C2; v.w *= C2; }
    uint2 pk;
    pk.x = pack_bf16x2(v.x, v.y);
    pk.y = pack_bf16x2(v.z, v.w);
    *reinterpret_cast<uint2*>(dst + j) = pk;
}

// -------- bf16 GEMM, C = A * B^T, 2-phase double-buffered staging ----------
// MODE 1: fp32 out + bias. MODE 2: qkv split (Q,K -> qk[.][1536]; V -> vT^T).
template <int MODE, int MROWS, int NF>
__global__ __launch_bounds__(256) void gemm_bt(
    const unsigned short* __restrict__ A,
    const unsigned short* __restrict__ B,
    unsigned short* __restrict__ Cb,
    unsigned short* __restrict__ Vt,
    float* __restrict__ Cf,
    const float* __restrict__ bias,
    int M, int N, int K)
{
    constexpr int MI = MROWS / 32;
    __shared__ __align__(16) unsigned short Al[2][MROWS * 64];
    __shared__ __align__(16) unsigned short Bl[2][NF * 32 * 64];
    const int bm   = blockIdx.x * MROWS;
    const int bn   = blockIdx.y * (NF * 32);
    const int tid  = (int)threadIdx.x;
    const int wave = tid >> 6;
    const int lane = tid & 63;
    const int wr   = wave >> 1;
    const int wc   = wave & 1;
    const int q    = lane & 15;
    const int g4   = (lane >> 4) * 4;

    f32x4 acc[MI][NF] = {};

    const int srow = lane >> 3;
    const int scol = (lane & 7) * 8;

    auto stage = [&](int buf, int k0) {
#pragma unroll
        for (int i = 0; i < MI; ++i) {
            const int chunk = wave * MI + i;
            GLOAD16(A + (size_t)(bm + chunk * 8 + srow) * K + (k0 + scol),
                    &Al[buf][chunk * 512]);
        }
#pragma unroll
        for (int i = 0; i < NF; ++i) {
            const int chunk = wave * NF + i;
            GLOAD16(B + (size_t)(bn + chunk * 8 + srow) * K + (k0 + scol),
                    &Bl[buf][chunk * 512]);
        }
    };

    stage(0, 0);
    __syncthreads();

    const int nt = K / 64;
    int buf = 0;
    for (int t = 0; t < nt; ++t) {
        if (t + 1 < nt) stage(buf ^ 1, (t + 1) * 64);   // issue before compute
#pragma unroll
        for (int kk = 0; kk < 2; ++kk) {
            const int ko = kk * 32 + (lane >> 4) * 8;
            bf16x8 af[MI], bf[NF];
#pragma unroll
            for (int mi = 0; mi < MI; ++mi)
                af[mi] = *(const bf16x8*)&Al[buf][(wr * (MROWS / 2) + mi * 16 + q) * 64 + ko];
#pragma unroll
            for (int ni = 0; ni < NF; ++ni)
                bf[ni] = *(const bf16x8*)&Bl[buf][(wc * 16 * NF + ni * 16 + q) * 64 + ko];
#pragma unroll
            for (int mi = 0; mi < MI; ++mi)
#pragma unroll
                for (int ni = 0; ni < NF; ++ni)
                    acc[mi][ni] = __builtin_amdgcn_mfma_f32_16x16x32_bf16(
                        af[mi], bf[ni], acc[mi][ni], 0, 0, 0);
        }
        __syncthreads();             // drains this iter's stage + closes reads
        buf ^= 1;
    }

#pragma unroll
    for (int mi = 0; mi < MI; ++mi) {
        const int row0 = bm + wr * (MROWS / 2) + mi * 16 + g4;
        if constexpr (MODE == 1) {
#pragma unroll
            for (int ni = 0; ni < NF; ++ni) {
                const int col = bn + wc * 16 * NF + ni * 16 + q;
#pragma unroll
                for (int r = 0; r < 4; ++r)
                    Cf[(size_t)(row0 + r) * N + col] = acc[mi][ni][r] + bias[col];
            }
        } else {
            if (bn < 1536) {
#pragma unroll
                for (int ni = 0; ni < NF; ++ni) {
                    const int col = bn + wc * 16 * NF + ni * 16 + q;
#pragma unroll
                    for (int r = 0; r < 4; ++r)
                        Cb[(size_t)(row0 + r) * 1536 + col] = f2bf(acc[mi][ni][r]);
                }
            } else {
                const int b  = row0 >> 11;
                const int np = row0 & 2047;
#pragma unroll
                for (int ni = 0; ni < NF; ++ni) {
                    const int vcol = bn + wc * 16 * NF + ni * 16 + q - 1536;
                    const int hv = vcol >> 6, d = vcol & 63;
                    uint2 w;
                    w.x = pack_bf16x2(acc[mi][ni][0], acc[mi][ni][1]);
                    w.y = pack_bf16x2(acc[mi][ni][2], acc[mi][ni][3]);
                    *reinterpret_cast<uint2*>(
                        &Vt[((size_t)(b * 12 + hv) * 64 + d) * 2048 + np]) = w;
                }
            }
        }
    }
}

// --- fused flash attention: kv-split waves, ALL LDS wave-private, 0 barriers
// qk: [B*N][1536] bf16 (Q pre-scaled, cols 0..768; K cols 768..1536)
// vT: [B*H*64][2048] bf16 ; out: [B*N][768] bf16
// Wave w owns kv rows [16w,16w+16) of every tile, ALL 64 q-cols.
// K LDS: [64 kv][64 d] (wave stages+reads own 16 rows). V LDS: per-wave
// private [64 d][16 kv] pitch-16. No __syncthreads in the main loop;
// per-wave counted vmcnt(4) only (T4).
__global__ __launch_bounds__(256, 3) void attn_fwd(
    const unsigned short* __restrict__ qk,
    const unsigned short* __restrict__ vT,
    const int* __restrict__ mask,
    unsigned short* __restrict__ out)
{
    const int NN = 2048, H = 12;
    const int bh = (int)blockIdx.y;
    const int b  = bh / H, h = bh % H;
    const int q0 = (int)blockIdx.x * 64;
    const int tid = (int)threadIdx.x, wave = tid >> 6, lane = tid & 63;
    const int g   = lane >> 4;
    const int q   = lane & 15;
    const int swz = (q & 7) << 3;

    // LDS: K 2x4096 | V 2x4096 | lbuf 256 f32  => 33792 B
    __shared__ __align__(16) unsigned short LDS[16896];
    unsigned short* Kl0 = LDS;           // [buf][kv 64][d 64]
    unsigned short* Vl0 = LDS + 8192;    // [buf][wave][d 64][kv 16]

    // wave-local mask vote: all 2048 entries nonzero?
    bool allone;
    {
        const int* mrow = mask + b * NN + lane * 32;
        unsigned mv = 0xFFFFFFFFu;
#pragma unroll
        for (int i = 0; i < 8; ++i) {
            int4 m = *reinterpret_cast<const int4*>(mrow + i * 4);
            mv = min(mv, min(min((unsigned)m.x, (unsigned)m.y),
                             min((unsigned)m.z, (unsigned)m.w)));
        }
        allone = __all(mv != 0u);
    }

    // Q B-fragments for all 4 q-tiles: B[k=d=kk*32+g*8+j][col=q0+16qt+q]
    bf16x8 qf[2][4];
#pragma unroll
    for (int kk = 0; kk < 2; ++kk)
#pragma unroll
        for (int qt = 0; qt < 4; ++qt)
            qf[kk][qt] = *reinterpret_cast<const bf16x8*>(
                &qk[(size_t)(b * NN + q0 + 16 * qt + q) * 1536 + h * 64 + kk * 32 + g * 8]);

    // K staging (own 16 kv rows; linear LDS dest, inverse-swizzled source col)
    const char* kg0 = (const char*)(qk + (size_t)(b * NN + wave * 16 + (lane >> 3)) * 1536
                                    + 768 + h * 64 + ((lane & 7) ^ (lane >> 3)) * 8);
    const char* kg1 = kg0 + (size_t)8 * 1536 * 2;
    // V staging (private [d][16]): call c covers d = c*32 + (lane>>1), half = lane&1
    const unsigned short* vgp = vT + (size_t)(bh * 64 + (lane >> 1)) * 2048
                                + 16 * wave + (lane & 1) * 8;

    auto stageK = [&](int buf) {
        GLOAD16(kg0, &Kl0[buf * 4096 + wave * 1024]);
        GLOAD16(kg1, &Kl0[buf * 4096 + wave * 1024 + 512]);
        kg0 += (size_t)64 * 1536 * 2;
        kg1 += (size_t)64 * 1536 * 2;
    };
    auto stageV = [&](int buf) {
        GLOAD16(vgp,                     &Vl0[buf * 4096 + wave * 1024]);
        GLOAD16(vgp + (size_t)32 * 2048, &Vl0[buf * 4096 + wave * 1024 + 512]);
        vgp += 64;                       // next kv tile (+64 cols)
    };

    f32x4 oacc[4][4] = {};          // [ct: d-tile][qt: q-tile]
    float l[4] = {0.f, 0.f, 0.f, 0.f};

    stageV(0); stageK(0);           // 4 loads in flight (no barrier needed)

    int cur = 0;
    for (int it = 0; it < 32; ++it) {
        if (it < 31) { stageV(cur ^ 1); stageK(cur ^ 1); }

        // wait this iter's 4 loads (issued last iter); next iter's stay in flight
        if (it < 31) asm volatile("s_waitcnt vmcnt(4)" ::: "memory");
        else         asm volatile("s_waitcnt vmcnt(0)" ::: "memory");

        // S^T[own 16 kv][64 q] = K_own * Q^T  (exp2 units; scale pre-folded)
        f32x4 s[4] = {};
        __builtin_amdgcn_s_setprio(1);
#pragma unroll
        for (int kk = 0; kk < 2; ++kk) {
            bf16x8 kf = *(const bf16x8*)&Kl0[cur * 4096 + (16 * wave + q) * 64
                                             + ((kk * 32 + g * 8) ^ swz)];
#pragma unroll
            for (int qt = 0; qt < 4; ++qt)
                s[qt] = __builtin_amdgcn_mfma_f32_16x16x32_bf16(kf, qf[kk][qt], s[qt], 0, 0, 0);
        }
        __builtin_amdgcn_s_setprio(0);

        if (!allone) {               // cold path: mask by absolute kv
            int4 mr = *reinterpret_cast<const int4*>(
                &mask[b * NN + it * 64 + 16 * wave + 4 * g]);
#pragma unroll
            for (int qt = 0; qt < 4; ++qt) {
                if (mr.x == 0) s[qt][0] = -INFINITY;
                if (mr.y == 0) s[qt][1] = -INFINITY;
                if (mr.z == 0) s[qt][2] = -INFINITY;
                if (mr.w == 0) s[qt][3] = -INFINITY;
            }
        }

        // p = exp2(s); per-lane l partials (reduced at epilogue); pack to bf16
        bf16x4 pb[4];
#pragma unroll
        for (int qt = 0; qt < 4; ++qt) {
            float p0 = __builtin_amdgcn_exp2f(s[qt][0]);
            float p1 = __builtin_amdgcn_exp2f(s[qt][1]);
            float p2 = __builtin_amdgcn_exp2f(s[qt][2]);
            float p3 = __builtin_amdgcn_exp2f(s[qt][3]);
            l[qt] += (p0 + p1) + (p2 + p3);
            uint2 t;
            t.x = pack_bf16x2(p0, p1);
            t.y = pack_bf16x2(p2, p3);
            pb[qt] = __builtin_bit_cast(bf16x4, t);
        }

        // O^T[64 d][64 q] partial += V_own^T * P^T  (P in registers)
        __builtin_amdgcn_s_setprio(1);
#pragma unroll
        for (int ct = 0; ct < 4; ++ct) {
            bf16x4 va = *(const bf16x4*)&Vl0[cur * 4096 + wave * 1024
                                             + (16 * ct + q) * 16 + 4 * g];
#pragma unroll
            for (int qt = 0; qt < 4; ++qt)
                oacc[ct][qt] = mfma16(va, pb[qt], oacc[ct][qt]);
        }
        __builtin_amdgcn_s_setprio(0);

        cur ^= 1;
    }

    __syncthreads();   // all waves done with K/V LDS before epilogue overlay

    // ---- epilogue: reduce l (over g, then waves) and O (over waves) ----
#pragma unroll
    for (int qt = 0; qt < 4; ++qt) {
        l[qt] += __shfl_xor(l[qt], 16);
        l[qt] += __shfl_xor(l[qt], 32);
    }
    float* lb = (float*)&LDS[16384];
    float* fb = (float*)&LDS[0];
    if (g == 0) {
#pragma unroll
        for (int qt = 0; qt < 4; ++qt) lb[wave * 64 + qt * 16 + q] = l[qt];
    }
    // round 1: waves 1,3 dump partials (16 KB each)
    if (wave & 1) {
        float* dst = fb + (wave >> 1) * 4096;
#pragma unroll
        for (int ct = 0; ct < 4; ++ct)
#pragma unroll
            for (int qt = 0; qt < 4; ++qt)
                *reinterpret_cast<f32x4*>(&dst[(ct * 4 + qt) * 256 + lane * 4]) = oacc[ct][qt];
    }
    __syncthreads();
    if (!(wave & 1)) {
        float* srcp = fb + (wave >> 1) * 4096;
#pragma unroll
        for (int ct = 0; ct < 4; ++ct)
#pragma unroll
            for (int qt = 0; qt < 4; ++qt)
                oacc[ct][qt] += *reinterpret_cast<f32x4*>(&srcp[(ct * 4 + qt) * 256 + lane * 4]);
    }
    __syncthreads();
    // round 2: wave 2 dumps merged partial
    if (wave == 2) {
#pragma unroll
        for (int ct = 0; ct < 4; ++ct)
#pragma unroll
            for (int qt = 0; qt < 4; ++qt)
                *reinterpret_cast<f32x4*>(&fb[(ct * 4 + qt) * 256 + lane * 4]) = oacc[ct][qt];
    }
    __syncthreads();
    if (wave == 0) {
        float inv[4];
#pragma unroll
        for (int qt = 0; qt < 4; ++qt)
            inv[qt] = 1.0f / (lb[qt * 16 + q] + lb[64 + qt * 16 + q]
                              + lb[128 + qt * 16 + q] + lb[192 + qt * 16 + q]);
#pragma unroll
        for (int ct = 0; ct < 4; ++ct)
#pragma unroll
            for (int qt = 0; qt < 4; ++qt) {
                f32x4 o = oacc[ct][qt]
                        + *reinterpret_cast<f32x4*>(&fb[(ct * 4 + qt) * 256 + lane * 4]);
                uint2 ow;
                ow.x = pack_bf16x2(o[0] * inv[qt], o[1] * inv[qt]);
                ow.y = pack_bf16x2(o[2] * inv[qt], o[3] * inv[qt]);
                *reinterpret_cast<uint2*>(
                    &out[(size_t)(b * NN + q0 + 16 * qt + q) * 768 + h * 64 + 16 * ct + 4 * g]) = ow;
            }
    }
}

// ---------------- host launch ----------------
extern "C" void kernel_launch(void* const* d_in, const int* in_sizes, int n_in,
                              void* d_out, int out_size, void* d_ws, size_t ws_size,
                              hipStream_t stream)
{
    const float* x      = (const float*)d_in[0];
    const int*   mask   = (const int*)d_in[1];
    const float* qkv_w  = (const float*)d_in[2];
    const float* proj_w = (const float*)d_in[3];
    const float* proj_b = (const float*)d_in[4];
    float* out = (float*)d_out;

    const int BN = 2 * 2048;
    const int C  = 768;
    const int C3 = 2304;

    char* w = (char*)d_ws;
    unsigned short* xb    = (unsigned short*)w; w += (size_t)BN * C    * 2;
    unsigned short* wqkv  = (unsigned short*)w; w += (size_t)C3 * C    * 2;
    unsigned short* wproj = (unsigned short*)w; w += (size_t)C  * C    * 2;
    unsigned short* qk    = (unsigned short*)w; w += (size_t)BN * 1536 * 2;
    unsigned short* vT    = (unsigned short*)w; w += (size_t)24 * 64 * 2048 * 2;
    unsigned short* ao    = (unsigned short*)w;

    // fused converts (Q weight rows pre-scaled by 0.125*log2e)
    {
        const int total = (BN * C + C3 * C + C * C) / 4;
        cvt_all<<<total / 256, 256, 0, stream>>>(x, qkv_w, proj_w, xb, wqkv, wproj);
    }

    // qkv GEMM with split epilogue: Q,K -> qk[.][1536]; V -> vT (transposed)
    gemm_bt<2, 128, 4><<<dim3(BN / 128, C3 / 128), 256, 0, stream>>>(
        xb, wqkv, qk, vT, nullptr, nullptr, BN, C3, C);

    attn_fwd<<<dim3(2048 / 64, 24), 256, 0, stream>>>(qk, vT, mask, ao);

    // out = ao @ proj_w^T + b (fp32), 128x64 tiles -> 384 blocks, 3/CU at 48KB
    gemm_bt<1, 128, 2><<<dim3(BN / 128, C / 64), 256, 0, stream>>>(
        ao, wproj, nullptr, nullptr, out, proj_b, BN, C, C);
}

// Round 10
// 105.080 us; speedup vs baseline: 1.6154x; 1.0471x over previous
//
#include <hip/hip_runtime.h>
#include <hip/hip_bf16.h>
#include <math.h>
#include <cstdint>
#include <cstddef>

typedef __bf16 bf16x8 __attribute__((ext_vector_type(8)));
typedef __bf16 bf16x4 __attribute__((ext_vector_type(4)));
typedef short  s16x4  __attribute__((ext_vector_type(4)));
typedef float  f32x4  __attribute__((ext_vector_type(4)));

#define GLOAD16(g, l) __builtin_amdgcn_global_load_lds( \
    (const __attribute__((address_space(1))) void*)(g),  \
    (__attribute__((address_space(3))) void*)(l), 16, 0, 0)

__device__ __forceinline__ unsigned short f2bf(float f) {
    union { float f; unsigned u; } v; v.f = f;
    unsigned u = v.u;
    u += 0x7fffu + ((u >> 16) & 1u);          // round-to-nearest-even
    return (unsigned short)(u >> 16);
}

__device__ __forceinline__ unsigned pack_bf16x2(float a, float b) {
    __hip_bfloat162 h = __float22bfloat162_rn(make_float2(a, b));
    return *reinterpret_cast<unsigned*>(&h);   // v_cvt_pk_bf16_f32
}

// 16x16x16 bf16 MFMA (2-VGPR A/B operands, kv as k-dim)
__device__ __forceinline__ f32x4 mfma16(bf16x4 a, bf16x4 b, f32x4 c) {
#if __has_builtin(__builtin_amdgcn_mfma_f32_16x16x16_bf16)
    return __builtin_amdgcn_mfma_f32_16x16x16_bf16(a, b, c, 0, 0, 0);
#elif __has_builtin(__builtin_amdgcn_mfma_f32_16x16x16bf16_1k)
    return __builtin_amdgcn_mfma_f32_16x16x16bf16_1k(
        __builtin_bit_cast(s16x4, a), __builtin_bit_cast(s16x4, b), c, 0, 0, 0);
#else
    asm volatile("v_mfma_f32_16x16x16_bf16 %0, %1, %2, %0"
                 : "+v"(c) : "v"(a), "v"(b));
    return c;
#endif
}

// ---- fused fp32 -> bf16 converts (x | qkv_w [Q rows pre-scaled] | proj_w) ----
__global__ __launch_bounds__(256) void cvt_all(
    const float* __restrict__ x,
    const float* __restrict__ qkvw,
    const float* __restrict__ projw,
    unsigned short* __restrict__ xb,
    unsigned short* __restrict__ wqkv,
    unsigned short* __restrict__ wproj)
{
    const int N1 = 4096 * 768;          // x
    const int N2 = 2304 * 768;          // qkv_w
    const int SC = 768 * 768;           // Q rows of qkv_w (scaled)
    const float C2 = 0.18033688011112042f;   // 0.125 * log2(e)
    int i = ((int)blockIdx.x * 256 + (int)threadIdx.x) * 4;

    const float* src;
    unsigned short* dst;
    int j;
    bool sc = false;
    if (i < N1)           { src = x;     dst = xb;    j = i; }
    else if (i < N1 + N2) { j = i - N1;  src = qkvw;  dst = wqkv;  sc = (j < SC); }
    else                  { j = i - N1 - N2; src = projw; dst = wproj; }

    float4 v = *reinterpret_cast<const float4*>(src + j);
    if (sc) { v.x *= C2; v.y *= C2; v.z *= C2; v.w *= C2; }
    uint2 pk;
    pk.x = pack_bf16x2(v.x, v.y);
    pk.y = pack_bf16x2(v.z, v.w);
    *reinterpret_cast<uint2*>(dst + j) = pk;
}

// -------- bf16 GEMM, C = A * B^T, 2-phase double-buffered staging ----------
// MODE 1: fp32 out + bias.
// MODE 2: qkv split — cols <1536 -> bf16 qk[row][1536]; V cols -> vT tiled:
//         vT[bhh][t][w][g][d][j]  (bhh=b*12+hv, t=np>>6, w=(np>>4)&3,
//         g=(np>>2)&3, j=np&3) — the exact LDS image attn stages.
template <int MODE, int MROWS, int NF>
__global__ __launch_bounds__(256) void gemm_bt(
    const unsigned short* __restrict__ A,
    const unsigned short* __restrict__ B,
    unsigned short* __restrict__ Cb,
    unsigned short* __restrict__ Vt,
    float* __restrict__ Cf,
    const float* __restrict__ bias,
    int M, int N, int K)
{
    constexpr int MI = MROWS / 32;
    __shared__ __align__(16) unsigned short Al[2][MROWS * 64];
    __shared__ __align__(16) unsigned short Bl[2][NF * 32 * 64];
    const int bm   = blockIdx.x * MROWS;
    const int bn   = blockIdx.y * (NF * 32);
    const int tid  = (int)threadIdx.x;
    const int wave = tid >> 6;
    const int lane = tid & 63;
    const int wr   = wave >> 1;
    const int wc   = wave & 1;
    const int q    = lane & 15;
    const int g4   = (lane >> 4) * 4;

    f32x4 acc[MI][NF] = {};

    const int srow = lane >> 3;
    const int scol = (lane & 7) * 8;

    auto stage = [&](int buf, int k0) {
#pragma unroll
        for (int i = 0; i < MI; ++i) {
            const int chunk = wave * MI + i;
            GLOAD16(A + (size_t)(bm + chunk * 8 + srow) * K + (k0 + scol),
                    &Al[buf][chunk * 512]);
        }
#pragma unroll
        for (int i = 0; i < NF; ++i) {
            const int chunk = wave * NF + i;
            GLOAD16(B + (size_t)(bn + chunk * 8 + srow) * K + (k0 + scol),
                    &Bl[buf][chunk * 512]);
        }
    };

    stage(0, 0);
    __syncthreads();

    const int nt = K / 64;
    int buf = 0;
    for (int t = 0; t < nt; ++t) {
        if (t + 1 < nt) stage(buf ^ 1, (t + 1) * 64);   // issue before compute
#pragma unroll
        for (int kk = 0; kk < 2; ++kk) {
            const int ko = kk * 32 + (lane >> 4) * 8;
            bf16x8 af[MI], bf[NF];
#pragma unroll
            for (int mi = 0; mi < MI; ++mi)
                af[mi] = *(const bf16x8*)&Al[buf][(wr * (MROWS / 2) + mi * 16 + q) * 64 + ko];
#pragma unroll
            for (int ni = 0; ni < NF; ++ni)
                bf[ni] = *(const bf16x8*)&Bl[buf][(wc * 16 * NF + ni * 16 + q) * 64 + ko];
#pragma unroll
            for (int mi = 0; mi < MI; ++mi)
#pragma unroll
                for (int ni = 0; ni < NF; ++ni)
                    acc[mi][ni] = __builtin_amdgcn_mfma_f32_16x16x32_bf16(
                        af[mi], bf[ni], acc[mi][ni], 0, 0, 0);
        }
        __syncthreads();             // drains this iter's stage + closes reads
        buf ^= 1;
    }

#pragma unroll
    for (int mi = 0; mi < MI; ++mi) {
        const int row0 = bm + wr * (MROWS / 2) + mi * 16 + g4;
        if constexpr (MODE == 1) {
#pragma unroll
            for (int ni = 0; ni < NF; ++ni) {
                const int col = bn + wc * 16 * NF + ni * 16 + q;
#pragma unroll
                for (int r = 0; r < 4; ++r)
                    Cf[(size_t)(row0 + r) * N + col] = acc[mi][ni][r] + bias[col];
            }
        } else {
            if (bn < 1536) {
#pragma unroll
                for (int ni = 0; ni < NF; ++ni) {
                    const int col = bn + wc * 16 * NF + ni * 16 + q;
#pragma unroll
                    for (int r = 0; r < 4; ++r)
                        Cb[(size_t)(row0 + r) * 1536 + col] = f2bf(acc[mi][ni][r]);
                }
            } else {
                const int bb  = row0 >> 11;
                const int np  = row0 & 2047;           // np % 4 == 0
                const int tt  = np >> 6;
                const int wv  = (np >> 4) & 3;
                const int gg  = (np >> 2) & 3;
#pragma unroll
                for (int ni = 0; ni < NF; ++ni) {
                    const int vcol = bn + wc * 16 * NF + ni * 16 + q - 1536;
                    const int hv = vcol >> 6, d = vcol & 63;
                    const size_t idx =
                        ((size_t)((bb * 12 + hv) * 32 + tt) * 4 + wv) * 1024
                        + gg * 256 + d * 4;
                    uint2 w;
                    w.x = pack_bf16x2(acc[mi][ni][0], acc[mi][ni][1]);
                    w.y = pack_bf16x2(acc[mi][ni][2], acc[mi][ni][3]);
                    *reinterpret_cast<uint2*>(&Vt[idx]) = w;   // coalesced 128B/group
                }
            }
        }
    }
}

// --- fused flash attention: kv-split waves, wave-private LDS, 0 barriers ---
// qk: [B*N][1536] bf16 (Q pre-scaled); vT tiled [bhh][t][w][g][d][j]
// 1D grid 768, XCD-chunked: xcd = bid&7 owns bh in {3*xcd..3*xcd+2}.
__global__ __launch_bounds__(256, 3) void attn_fwd(
    const unsigned short* __restrict__ qk,
    const unsigned short* __restrict__ vT,
    const int* __restrict__ mask,
    unsigned short* __restrict__ out)
{
    const int NN = 2048, H = 12;
    const int bid = (int)blockIdx.x;
    const int bhh = (bid & 7) * 3 + ((bid >> 3) >> 5);   // 0..23
    const int qt  = (bid >> 3) & 31;
    const int b   = bhh / H, h = bhh % H;
    const int q0  = qt * 64;
    const int tid = (int)threadIdx.x, wave = tid >> 6, lane = tid & 63;
    const int g   = lane >> 4;
    const int q   = lane & 15;
    const int swz = (q & 7) << 3;

    // LDS: K 2x4096 | V 2x4096 | lbuf 256 f32  => 33792 B
    __shared__ __align__(16) unsigned short LDS[16896];
    unsigned short* Kl0 = LDS;           // [buf][kv 64][d 64]
    unsigned short* Vl0 = LDS + 8192;    // [buf][wave][g 4][d 64][j 4]

    // wave-local mask vote: all 2048 entries nonzero?
    bool allone;
    {
        const int* mrow = mask + b * NN + lane * 32;
        unsigned mv = 0xFFFFFFFFu;
#pragma unroll
        for (int i = 0; i < 8; ++i) {
            int4 m = *reinterpret_cast<const int4*>(mrow + i * 4);
            mv = min(mv, min(min((unsigned)m.x, (unsigned)m.y),
                             min((unsigned)m.z, (unsigned)m.w)));
        }
        allone = __all(mv != 0u);
    }

    // Q B-fragments for all 4 q-tiles: B[k=d=kk*32+g*8+j][col=q0+16qt+q]
    bf16x8 qf[2][4];
#pragma unroll
    for (int kk = 0; kk < 2; ++kk)
#pragma unroll
        for (int qtl = 0; qtl < 4; ++qtl)
            qf[kk][qtl] = *reinterpret_cast<const bf16x8*>(
                &qk[(size_t)(b * NN + q0 + 16 * qtl + q) * 1536 + h * 64 + kk * 32 + g * 8]);

    // K staging (own 16 kv rows; linear LDS dest, inverse-swizzled source col)
    const char* kg0 = (const char*)(qk + (size_t)(b * NN + wave * 16 + (lane >> 3)) * 1536
                                    + 768 + h * 64 + ((lane & 7) ^ (lane >> 3)) * 8);
    const char* kg1 = kg0 + (size_t)8 * 1536 * 2;
    // V staging: vT tiled layout — perfectly linear, lane*16B
    const unsigned short* vgp = vT + ((size_t)bhh * 32 * 4 + wave) * 1024 + lane * 8;

    auto stageK = [&](int buf) {
        GLOAD16(kg0, &Kl0[buf * 4096 + wave * 1024]);
        GLOAD16(kg1, &Kl0[buf * 4096 + wave * 1024 + 512]);
        kg0 += (size_t)64 * 1536 * 2;
        kg1 += (size_t)64 * 1536 * 2;
    };
    auto stageV = [&](int buf) {
        GLOAD16(vgp,       &Vl0[buf * 4096 + wave * 1024]);
        GLOAD16(vgp + 512, &Vl0[buf * 4096 + wave * 1024 + 512]);
        vgp += 4096;                     // next kv tile
    };

    f32x4 oacc[4][4] = {};          // [ct: d-tile][qt: q-tile]
    float l[4] = {0.f, 0.f, 0.f, 0.f};

    stageK(0); stageV(0);           // 4 loads in flight (no barrier needed)

    int cur = 0;
    for (int it = 0; it < 32; ++it) {
        if (it < 31) { stageK(cur ^ 1); stageV(cur ^ 1); }

        // K(it) resident; V(it) + next iter's 4 stay in flight
        if (it < 31) asm volatile("s_waitcnt vmcnt(6)" ::: "memory");
        else         asm volatile("s_waitcnt vmcnt(2)" ::: "memory");

        // S^T[own 16 kv][64 q] = K_own * Q^T  (exp2 units; scale pre-folded)
        f32x4 s[4] = {};
        __builtin_amdgcn_s_setprio(1);
#pragma unroll
        for (int kk = 0; kk < 2; ++kk) {
            bf16x8 kf = *(const bf16x8*)&Kl0[cur * 4096 + (16 * wave + q) * 64
                                             + ((kk * 32 + g * 8) ^ swz)];
#pragma unroll
            for (int qtl = 0; qtl < 4; ++qtl)
                s[qtl] = __builtin_amdgcn_mfma_f32_16x16x32_bf16(kf, qf[kk][qtl], s[qtl], 0, 0, 0);
        }
        __builtin_amdgcn_s_setprio(0);

        if (!allone) {               // cold path: mask by absolute kv
            int4 mr = *reinterpret_cast<const int4*>(
                &mask[b * NN + it * 64 + 16 * wave + 4 * g]);
#pragma unroll
            for (int qtl = 0; qtl < 4; ++qtl) {
                if (mr.x == 0) s[qtl][0] = -INFINITY;
                if (mr.y == 0) s[qtl][1] = -INFINITY;
                if (mr.z == 0) s[qtl][2] = -INFINITY;
                if (mr.w == 0) s[qtl][3] = -INFINITY;
            }
        }

        // p = exp2(s); per-lane l partials (reduced at epilogue); pack to bf16
        bf16x4 pb[4];
#pragma unroll
        for (int qtl = 0; qtl < 4; ++qtl) {
            float p0 = __builtin_amdgcn_exp2f(s[qtl][0]);
            float p1 = __builtin_amdgcn_exp2f(s[qtl][1]);
            float p2 = __builtin_amdgcn_exp2f(s[qtl][2]);
            float p3 = __builtin_amdgcn_exp2f(s[qtl][3]);
            l[qtl] += (p0 + p1) + (p2 + p3);
            uint2 t;
            t.x = pack_bf16x2(p0, p1);
            t.y = pack_bf16x2(p2, p3);
            pb[qtl] = __builtin_bit_cast(bf16x4, t);
        }

        // V(it) resident; next iter's 4 remain in flight
        if (it < 31) asm volatile("s_waitcnt vmcnt(4)" ::: "memory");
        else         asm volatile("s_waitcnt vmcnt(0)" ::: "memory");

        // O^T[64 d][64 q] partial += V_own^T * P^T  (P in registers)
        __builtin_amdgcn_s_setprio(1);
#pragma unroll
        for (int ct = 0; ct < 4; ++ct) {
            // [g][d][j] layout: banks 2q,2q+1 -> conflict-free
            bf16x4 va = *(const bf16x4*)&Vl0[cur * 4096 + wave * 1024
                                             + g * 256 + (16 * ct + q) * 4];
#pragma unroll
            for (int qtl = 0; qtl < 4; ++qtl)
                oacc[ct][qtl] = mfma16(va, pb[qtl], oacc[ct][qtl]);
        }
        __builtin_amdgcn_s_setprio(0);

        cur ^= 1;
    }

    __syncthreads();   // all waves done with K/V LDS before epilogue overlay

    // ---- epilogue: reduce l (over g, then waves) and O (over waves) ----
#pragma unroll
    for (int qtl = 0; qtl < 4; ++qtl) {
        l[qtl] += __shfl_xor(l[qtl], 16);
        l[qtl] += __shfl_xor(l[qtl], 32);
    }
    float* lb = (float*)&LDS[16384];
    float* fb = (float*)&LDS[0];
    if (g == 0) {
#pragma unroll
        for (int qtl = 0; qtl < 4; ++qtl) lb[wave * 64 + qtl * 16 + q] = l[qtl];
    }
    // round 1: waves 1,3 dump partials (16 KB each)
    if (wave & 1) {
        float* dst = fb + (wave >> 1) * 4096;
#pragma unroll
        for (int ct = 0; ct < 4; ++ct)
#pragma unroll
            for (int qtl = 0; qtl < 4; ++qtl)
                *reinterpret_cast<f32x4*>(&dst[(ct * 4 + qtl) * 256 + lane * 4]) = oacc[ct][qtl];
    }
    __syncthreads();
    if (!(wave & 1)) {
        float* srcp = fb + (wave >> 1) * 4096;
#pragma unroll
        for (int ct = 0; ct < 4; ++ct)
#pragma unroll
            for (int qtl = 0; qtl < 4; ++qtl)
                oacc[ct][qtl] += *reinterpret_cast<f32x4*>(&srcp[(ct * 4 + qtl) * 256 + lane * 4]);
    }
    __syncthreads();
    // round 2: wave 2 dumps merged partial
    if (wave == 2) {
#pragma unroll
        for (int ct = 0; ct < 4; ++ct)
#pragma unroll
            for (int qtl = 0; qtl < 4; ++qtl)
                *reinterpret_cast<f32x4*>(&fb[(ct * 4 + qtl) * 256 + lane * 4]) = oacc[ct][qtl];
    }
    __syncthreads();
    if (wave == 0) {
        float inv[4];
#pragma unroll
        for (int qtl = 0; qtl < 4; ++qtl)
            inv[qtl] = 1.0f / (lb[qtl * 16 + q] + lb[64 + qtl * 16 + q]
                              + lb[128 + qtl * 16 + q] + lb[192 + qtl * 16 + q]);
#pragma unroll
        for (int ct = 0; ct < 4; ++ct)
#pragma unroll
            for (int qtl = 0; qtl < 4; ++qtl) {
                f32x4 o = oacc[ct][qtl]
                        + *reinterpret_cast<f32x4*>(&fb[(ct * 4 + qtl) * 256 + lane * 4]);
                uint2 ow;
                ow.x = pack_bf16x2(o[0] * inv[qtl], o[1] * inv[qtl]);
                ow.y = pack_bf16x2(o[2] * inv[qtl], o[3] * inv[qtl]);
                *reinterpret_cast<uint2*>(
                    &out[(size_t)(b * NN + q0 + 16 * qtl + q) * 768 + h * 64 + 16 * ct + 4 * g]) = ow;
            }
    }
}

// ---------------- host launch ----------------
extern "C" void kernel_launch(void* const* d_in, const int* in_sizes, int n_in,
                              void* d_out, int out_size, void* d_ws, size_t ws_size,
                              hipStream_t stream)
{
    const float* x      = (const float*)d_in[0];
    const int*   mask   = (const int*)d_in[1];
    const float* qkv_w  = (const float*)d_in[2];
    const float* proj_w = (const float*)d_in[3];
    const float* proj_b = (const float*)d_in[4];
    float* out = (float*)d_out;

    const int BN = 2 * 2048;
    const int C  = 768;
    const int C3 = 2304;

    char* w = (char*)d_ws;
    unsigned short* xb    = (unsigned short*)w; w += (size_t)BN * C    * 2;
    unsigned short* wqkv  = (unsigned short*)w; w += (size_t)C3 * C    * 2;
    unsigned short* wproj = (unsigned short*)w; w += (size_t)C  * C    * 2;
    unsigned short* qk    = (unsigned short*)w; w += (size_t)BN * 1536 * 2;
    unsigned short* vT    = (unsigned short*)w; w += (size_t)24 * 64 * 2048 * 2;
    unsigned short* ao    = (unsigned short*)w;

    // fused converts (Q weight rows pre-scaled by 0.125*log2e)
    {
        const int total = (BN * C + C3 * C + C * C) / 4;
        cvt_all<<<total / 256, 256, 0, stream>>>(x, qkv_w, proj_w, xb, wqkv, wproj);
    }

    // qkv GEMM with split epilogue: Q,K -> qk[.][1536]; V -> vT (tiled layout)
    gemm_bt<2, 128, 4><<<dim3(BN / 128, C3 / 128), 256, 0, stream>>>(
        xb, wqkv, qk, vT, nullptr, nullptr, BN, C3, C);

    attn_fwd<<<dim3(768), 256, 0, stream>>>(qk, vT, mask, ao);

    // out = ao @ proj_w^T + b (fp32), 64x64 tiles -> 768 blocks (3/CU balanced)
    gemm_bt<1, 64, 2><<<dim3(BN / 64, C / 64), 256, 0, stream>>>(
        ao, wproj, nullptr, nullptr, out, proj_b, BN, C, C);
}

// Round 11
// 103.769 us; speedup vs baseline: 1.6358x; 1.0126x over previous
//
#include <hip/hip_runtime.h>
#include <hip/hip_bf16.h>
#include <math.h>
#include <cstdint>
#include <cstddef>

typedef __bf16 bf16x8 __attribute__((ext_vector_type(8)));
typedef __bf16 bf16x4 __attribute__((ext_vector_type(4)));
typedef short  s16x4  __attribute__((ext_vector_type(4)));
typedef float  f32x4  __attribute__((ext_vector_type(4)));

#define GLOAD16(g, l) __builtin_amdgcn_global_load_lds( \
    (const __attribute__((address_space(1))) void*)(g),  \
    (__attribute__((address_space(3))) void*)(l), 16, 0, 0)

__device__ __forceinline__ unsigned short f2bf(float f) {
    union { float f; unsigned u; } v; v.f = f;
    unsigned u = v.u;
    u += 0x7fffu + ((u >> 16) & 1u);          // round-to-nearest-even
    return (unsigned short)(u >> 16);
}

__device__ __forceinline__ unsigned pack_bf16x2(float a, float b) {
    __hip_bfloat162 h = __float22bfloat162_rn(make_float2(a, b));
    return *reinterpret_cast<unsigned*>(&h);   // v_cvt_pk_bf16_f32
}

// 16x16x16 bf16 MFMA (2-VGPR A/B operands, kv as k-dim)
__device__ __forceinline__ f32x4 mfma16(bf16x4 a, bf16x4 b, f32x4 c) {
#if __has_builtin(__builtin_amdgcn_mfma_f32_16x16x16_bf16)
    return __builtin_amdgcn_mfma_f32_16x16x16_bf16(a, b, c, 0, 0, 0);
#elif __has_builtin(__builtin_amdgcn_mfma_f32_16x16x16bf16_1k)
    return __builtin_amdgcn_mfma_f32_16x16x16bf16_1k(
        __builtin_bit_cast(s16x4, a), __builtin_bit_cast(s16x4, b), c, 0, 0, 0);
#else
    asm volatile("v_mfma_f32_16x16x16_bf16 %0, %1, %2, %0"
                 : "+v"(c) : "v"(a), "v"(b));
    return c;
#endif
}

// ---- fused fp32 -> bf16 converts (x | qkv_w [Q rows pre-scaled] | proj_w) ----
__global__ __launch_bounds__(256) void cvt_all(
    const float* __restrict__ x,
    const float* __restrict__ qkvw,
    const float* __restrict__ projw,
    unsigned short* __restrict__ xb,
    unsigned short* __restrict__ wqkv,
    unsigned short* __restrict__ wproj)
{
    const int N1 = 4096 * 768;          // x
    const int N2 = 2304 * 768;          // qkv_w
    const int SC = 768 * 768;           // Q rows of qkv_w (scaled)
    const float C2 = 0.18033688011112042f;   // 0.125 * log2(e)
    int i = ((int)blockIdx.x * 256 + (int)threadIdx.x) * 4;

    const float* src;
    unsigned short* dst;
    int j;
    bool sc = false;
    if (i < N1)           { src = x;     dst = xb;    j = i; }
    else if (i < N1 + N2) { j = i - N1;  src = qkvw;  dst = wqkv;  sc = (j < SC); }
    else                  { j = i - N1 - N2; src = projw; dst = wproj; }

    float4 v = *reinterpret_cast<const float4*>(src + j);
    if (sc) { v.x *= C2; v.y *= C2; v.z *= C2; v.w *= C2; }
    uint2 pk;
    pk.x = pack_bf16x2(v.x, v.y);
    pk.y = pack_bf16x2(v.z, v.w);
    *reinterpret_cast<uint2*>(dst + j) = pk;
}

// -------- bf16 GEMM, C = A * B^T, 2-phase dbuf, T2 XOR-swizzled LDS --------
// MODE 1: fp32 out + bias.
// MODE 2: qkv split — cols <1536 -> bf16 qk[row][1536]; V cols -> vT tiled:
//         vT[bhh][t][w][g][d][j] — the exact LDS image attn stages.
template <int MODE, int MROWS, int NF>
__global__ __launch_bounds__(256) void gemm_bt(
    const unsigned short* __restrict__ A,
    const unsigned short* __restrict__ B,
    unsigned short* __restrict__ Cb,
    unsigned short* __restrict__ Vt,
    float* __restrict__ Cf,
    const float* __restrict__ bias,
    int M, int N, int K)
{
    constexpr int MI = MROWS / 32;
    __shared__ __align__(16) unsigned short Al[2][MROWS * 64];
    __shared__ __align__(16) unsigned short Bl[2][NF * 32 * 64];
    const int bm   = blockIdx.x * MROWS;
    const int bn   = blockIdx.y * (NF * 32);
    const int tid  = (int)threadIdx.x;
    const int wave = tid >> 6;
    const int lane = tid & 63;
    const int wr   = wave >> 1;
    const int wc   = wave & 1;
    const int q    = lane & 15;
    const int g4   = (lane >> 4) * 4;
    const int swz  = (q & 7) << 3;       // read-side XOR (elems)

    f32x4 acc[MI][NF] = {};

    const int srow = lane >> 3;
    const int scol = ((lane & 7) ^ srow) * 8;   // inverse-swizzled source col

    auto stage = [&](int buf, int k0) {
#pragma unroll
        for (int i = 0; i < MI; ++i) {
            const int chunk = wave * MI + i;
            GLOAD16(A + (size_t)(bm + chunk * 8 + srow) * K + (k0 + scol),
                    &Al[buf][chunk * 512]);
        }
#pragma unroll
        for (int i = 0; i < NF; ++i) {
            const int chunk = wave * NF + i;
            GLOAD16(B + (size_t)(bn + chunk * 8 + srow) * K + (k0 + scol),
                    &Bl[buf][chunk * 512]);
        }
    };

    stage(0, 0);
    __syncthreads();

    const int nt = K / 64;
    int buf = 0;
    for (int t = 0; t < nt; ++t) {
        if (t + 1 < nt) stage(buf ^ 1, (t + 1) * 64);   // issue before compute
#pragma unroll
        for (int kk = 0; kk < 2; ++kk) {
            const int ko = kk * 32 + (lane >> 4) * 8;
            bf16x8 af[MI], bf[NF];
#pragma unroll
            for (int mi = 0; mi < MI; ++mi)
                af[mi] = *(const bf16x8*)&Al[buf][(wr * (MROWS / 2) + mi * 16 + q) * 64
                                                  + (ko ^ swz)];
#pragma unroll
            for (int ni = 0; ni < NF; ++ni)
                bf[ni] = *(const bf16x8*)&Bl[buf][(wc * 16 * NF + ni * 16 + q) * 64
                                                  + (ko ^ swz)];
#pragma unroll
            for (int mi = 0; mi < MI; ++mi)
#pragma unroll
                for (int ni = 0; ni < NF; ++ni)
                    acc[mi][ni] = __builtin_amdgcn_mfma_f32_16x16x32_bf16(
                        af[mi], bf[ni], acc[mi][ni], 0, 0, 0);
        }
        __syncthreads();             // drains this iter's stage + closes reads
        buf ^= 1;
    }

#pragma unroll
    for (int mi = 0; mi < MI; ++mi) {
        const int row0 = bm + wr * (MROWS / 2) + mi * 16 + g4;
        if constexpr (MODE == 1) {
#pragma unroll
            for (int ni = 0; ni < NF; ++ni) {
                const int col = bn + wc * 16 * NF + ni * 16 + q;
#pragma unroll
                for (int r = 0; r < 4; ++r)
                    Cf[(size_t)(row0 + r) * N + col] = acc[mi][ni][r] + bias[col];
            }
        } else {
            if (bn < 1536) {
#pragma unroll
                for (int ni = 0; ni < NF; ++ni) {
                    const int col = bn + wc * 16 * NF + ni * 16 + q;
#pragma unroll
                    for (int r = 0; r < 4; ++r)
                        Cb[(size_t)(row0 + r) * 1536 + col] = f2bf(acc[mi][ni][r]);
                }
            } else {
                const int bb  = row0 >> 11;
                const int np  = row0 & 2047;           // np % 4 == 0
                const int tt  = np >> 6;
                const int wv  = (np >> 4) & 3;
                const int gg  = (np >> 2) & 3;
#pragma unroll
                for (int ni = 0; ni < NF; ++ni) {
                    const int vcol = bn + wc * 16 * NF + ni * 16 + q - 1536;
                    const int hv = vcol >> 6, d = vcol & 63;
                    const size_t idx =
                        ((size_t)((bb * 12 + hv) * 32 + tt) * 4 + wv) * 1024
                        + gg * 256 + d * 4;
                    uint2 w;
                    w.x = pack_bf16x2(acc[mi][ni][0], acc[mi][ni][1]);
                    w.y = pack_bf16x2(acc[mi][ni][2], acc[mi][ni][3]);
                    *reinterpret_cast<uint2*>(&Vt[idx]) = w;   // coalesced
                }
            }
        }
    }
}

// --- fused flash attention: kv-split waves, software-pipelined QK(t+1) ----
// qk: [B*N][1536] bf16 (Q pre-scaled); vT tiled [bhh][t][w][g][d][j]
// 1D grid 768, XCD-chunked. Per iter: softmax(t) | QK(t+1) | PV(t), one
// counted vmcnt(6) per iter (guarantees K(t+1) and V(t)). V 3-deep, K 2-deep.
__global__ __launch_bounds__(256, 3) void attn_fwd(
    const unsigned short* __restrict__ qk,
    const unsigned short* __restrict__ vT,
    const int* __restrict__ mask,
    unsigned short* __restrict__ out)
{
    const int NN = 2048, H = 12;
    const int bid = (int)blockIdx.x;
    const int bhh = (bid & 7) * 3 + ((bid >> 3) >> 5);   // 0..23
    const int qt  = (bid >> 3) & 31;
    const int b   = bhh / H, h = bhh % H;
    const int q0  = qt * 64;
    const int tid = (int)threadIdx.x, wave = tid >> 6, lane = tid & 63;
    const int g   = lane >> 4;
    const int q   = lane & 15;
    const int swz = (q & 7) << 3;

    // LDS: K 2x4096 | V 3x4096  => 40960 B (epilogue overlays f32 scratch)
    __shared__ __align__(16) unsigned short LDS[20480];
    unsigned short* Kl0 = LDS;           // [buf2][kv 64][d 64]
    unsigned short* Vl0 = LDS + 8192;    // [buf3][wave][g 4][d 64][j 4]

    // wave-local mask vote: all 2048 entries nonzero?
    bool allone;
    {
        const int* mrow = mask + b * NN + lane * 32;
        unsigned mv = 0xFFFFFFFFu;
#pragma unroll
        for (int i = 0; i < 8; ++i) {
            int4 m = *reinterpret_cast<const int4*>(mrow + i * 4);
            mv = min(mv, min(min((unsigned)m.x, (unsigned)m.y),
                             min((unsigned)m.z, (unsigned)m.w)));
        }
        allone = __all(mv != 0u);
    }

    // Q B-fragments for all 4 q-tiles: B[k=d=kk*32+g*8+j][col=q0+16qt+q]
    bf16x8 qf[2][4];
#pragma unroll
    for (int kk = 0; kk < 2; ++kk)
#pragma unroll
        for (int qtl = 0; qtl < 4; ++qtl)
            qf[kk][qtl] = *reinterpret_cast<const bf16x8*>(
                &qk[(size_t)(b * NN + q0 + 16 * qtl + q) * 1536 + h * 64 + kk * 32 + g * 8]);

    // K staging (own 16 kv rows; linear LDS dest, inverse-swizzled source col)
    const char* kg0 = (const char*)(qk + (size_t)(b * NN + wave * 16 + (lane >> 3)) * 1536
                                    + 768 + h * 64 + ((lane & 7) ^ (lane >> 3)) * 8);
    const char* kg1 = kg0 + (size_t)8 * 1536 * 2;
    // V staging: vT tiled layout — perfectly linear, lane*16B
    const unsigned short* vgp = vT + ((size_t)bhh * 32 * 4 + wave) * 1024 + lane * 8;

    auto stageK = [&](int buf) {
        GLOAD16(kg0, &Kl0[buf * 4096 + wave * 1024]);
        GLOAD16(kg1, &Kl0[buf * 4096 + wave * 1024 + 512]);
        kg0 += (size_t)64 * 1536 * 2;
        kg1 += (size_t)64 * 1536 * 2;
    };
    auto stageV = [&](int buf) {
        GLOAD16(vgp,       &Vl0[buf * 4096 + wave * 1024]);
        GLOAD16(vgp + 512, &Vl0[buf * 4096 + wave * 1024 + 512]);
        vgp += 4096;                     // next kv tile
    };

    f32x4 oacc[4][4] = {};          // [ct: d-tile][qtl: q-tile] (AGPR-backed)
    float l[4] = {0.f, 0.f, 0.f, 0.f};
    f32x4 sA[4], sB[4];

    // QK of tile t from K buf kb into sdst
    auto qkstep = [&](f32x4* sdst, int kb) {
        __builtin_amdgcn_s_setprio(1);
#pragma unroll
        for (int kk = 0; kk < 2; ++kk) {
            bf16x8 kf = *(const bf16x8*)&Kl0[kb * 4096 + (16 * wave + q) * 64
                                             + ((kk * 32 + g * 8) ^ swz)];
#pragma unroll
            for (int qtl = 0; qtl < 4; ++qtl)
                sdst[qtl] = __builtin_amdgcn_mfma_f32_16x16x32_bf16(
                    kf, qf[kk][qtl], sdst[qtl], 0, 0, 0);
        }
        __builtin_amdgcn_s_setprio(0);
    };

    // prologue: tiles 0,1 staged; compute S(0)
    stageK(0); stageV(0); stageK(1); stageV(1);
    asm volatile("s_waitcnt vmcnt(6)" ::: "memory");
#pragma unroll
    for (int qtl = 0; qtl < 4; ++qtl) sA[qtl] = f32x4{0.f, 0.f, 0.f, 0.f};
    qkstep(sA, 0);

    int vcur = 0, vstg = 2;
    bf16x4 pb[4];

    auto body = [&](f32x4* scur, f32x4* snxt, int t) {
        // ---- softmax of tile t (VALU; interleaves with QK below) ----
        if (!allone) {
            int4 mr = *reinterpret_cast<const int4*>(
                &mask[b * NN + t * 64 + 16 * wave + 4 * g]);
#pragma unroll
            for (int qtl = 0; qtl < 4; ++qtl) {
                if (mr.x == 0) scur[qtl][0] = -INFINITY;
                if (mr.y == 0) scur[qtl][1] = -INFINITY;
                if (mr.z == 0) scur[qtl][2] = -INFINITY;
                if (mr.w == 0) scur[qtl][3] = -INFINITY;
            }
        }
#pragma unroll
        for (int qtl = 0; qtl < 4; ++qtl) {
            float p0 = __builtin_amdgcn_exp2f(scur[qtl][0]);
            float p1 = __builtin_amdgcn_exp2f(scur[qtl][1]);
            float p2 = __builtin_amdgcn_exp2f(scur[qtl][2]);
            float p3 = __builtin_amdgcn_exp2f(scur[qtl][3]);
            l[qtl] += (p0 + p1) + (p2 + p3);
            uint2 tt;
            tt.x = pack_bf16x2(p0, p1);
            tt.y = pack_bf16x2(p2, p3);
            pb[qtl] = __builtin_bit_cast(bf16x4, tt);
        }

        // ---- stage tile t+2 ----
        if (t <= 29) { stageK(t & 1); stageV(vstg); }
        vstg = (vstg == 2) ? 0 : vstg + 1;

        // ---- one counted wait: K(t+1) and V(t) resident ----
        if (t <= 29)      asm volatile("s_waitcnt vmcnt(6)" ::: "memory");
        else if (t == 30) asm volatile("s_waitcnt vmcnt(2)" ::: "memory");
        else              asm volatile("s_waitcnt vmcnt(0)" ::: "memory");

        // ---- QK of tile t+1 (MFMA; independent of softmax above) ----
        if (t <= 30) {
#pragma unroll
            for (int qtl = 0; qtl < 4; ++qtl) snxt[qtl] = f32x4{0.f, 0.f, 0.f, 0.f};
            qkstep(snxt, (t + 1) & 1);
        }

        // ---- PV of tile t ----
        __builtin_amdgcn_s_setprio(1);
#pragma unroll
        for (int ct = 0; ct < 4; ++ct) {
            bf16x4 va = *(const bf16x4*)&Vl0[vcur * 4096 + wave * 1024
                                             + g * 256 + (16 * ct + q) * 4];
#pragma unroll
            for (int qtl = 0; qtl < 4; ++qtl)
                oacc[ct][qtl] = mfma16(va, pb[qtl], oacc[ct][qtl]);
        }
        __builtin_amdgcn_s_setprio(0);
        vcur = (vcur == 2) ? 0 : vcur + 1;
    };

    for (int tt = 0; tt < 16; ++tt) {
        body(sA, sB, 2 * tt);
        body(sB, sA, 2 * tt + 1);
    }

    __syncthreads();   // all waves done with K/V LDS before epilogue overlay

    // ---- epilogue: reduce l (over g, then waves) and O (over waves) ----
#pragma unroll
    for (int qtl = 0; qtl < 4; ++qtl) {
        l[qtl] += __shfl_xor(l[qtl], 16);
        l[qtl] += __shfl_xor(l[qtl], 32);
    }
    float* lb = (float*)&LDS[16384];
    float* fb = (float*)&LDS[0];
    if (g == 0) {
#pragma unroll
        for (int qtl = 0; qtl < 4; ++qtl) lb[wave * 64 + qtl * 16 + q] = l[qtl];
    }
    // round 1: waves 1,3 dump partials (16 KB each)
    if (wave & 1) {
        float* dst = fb + (wave >> 1) * 4096;
#pragma unroll
        for (int ct = 0; ct < 4; ++ct)
#pragma unroll
            for (int qtl = 0; qtl < 4; ++qtl)
                *reinterpret_cast<f32x4*>(&dst[(ct * 4 + qtl) * 256 + lane * 4]) = oacc[ct][qtl];
    }
    __syncthreads();
    if (!(wave & 1)) {
        float* srcp = fb + (wave >> 1) * 4096;
#pragma unroll
        for (int ct = 0; ct < 4; ++ct)
#pragma unroll
            for (int qtl = 0; qtl < 4; ++qtl)
                oacc[ct][qtl] += *reinterpret_cast<f32x4*>(&srcp[(ct * 4 + qtl) * 256 + lane * 4]);
    }
    __syncthreads();
    // round 2: wave 2 dumps merged partial
    if (wave == 2) {
#pragma unroll
        for (int ct = 0; ct < 4; ++ct)
#pragma unroll
            for (int qtl = 0; qtl < 4; ++qtl)
                *reinterpret_cast<f32x4*>(&fb[(ct * 4 + qtl) * 256 + lane * 4]) = oacc[ct][qtl];
    }
    __syncthreads();
    if (wave == 0) {
        float inv[4];
#pragma unroll
        for (int qtl = 0; qtl < 4; ++qtl)
            inv[qtl] = 1.0f / (lb[qtl * 16 + q] + lb[64 + qtl * 16 + q]
                              + lb[128 + qtl * 16 + q] + lb[192 + qtl * 16 + q]);
#pragma unroll
        for (int ct = 0; ct < 4; ++ct)
#pragma unroll
            for (int qtl = 0; qtl < 4; ++qtl) {
                f32x4 o = oacc[ct][qtl]
                        + *reinterpret_cast<f32x4*>(&fb[(ct * 4 + qtl) * 256 + lane * 4]);
                uint2 ow;
                ow.x = pack_bf16x2(o[0] * inv[qtl], o[1] * inv[qtl]);
                ow.y = pack_bf16x2(o[2] * inv[qtl], o[3] * inv[qtl]);
                *reinterpret_cast<uint2*>(
                    &out[(size_t)(b * NN + q0 + 16 * qtl + q) * 768 + h * 64 + 16 * ct + 4 * g]) = ow;
            }
    }
}

// ---------------- host launch ----------------
extern "C" void kernel_launch(void* const* d_in, const int* in_sizes, int n_in,
                              void* d_out, int out_size, void* d_ws, size_t ws_size,
                              hipStream_t stream)
{
    const float* x      = (const float*)d_in[0];
    const int*   mask   = (const int*)d_in[1];
    const float* qkv_w  = (const float*)d_in[2];
    const float* proj_w = (const float*)d_in[3];
    const float* proj_b = (const float*)d_in[4];
    float* out = (float*)d_out;

    const int BN = 2 * 2048;
    const int C  = 768;
    const int C3 = 2304;

    char* w = (char*)d_ws;
    unsigned short* xb    = (unsigned short*)w; w += (size_t)BN * C    * 2;
    unsigned short* wqkv  = (unsigned short*)w; w += (size_t)C3 * C    * 2;
    unsigned short* wproj = (unsigned short*)w; w += (size_t)C  * C    * 2;
    unsigned short* qk    = (unsigned short*)w; w += (size_t)BN * 1536 * 2;
    unsigned short* vT    = (unsigned short*)w; w += (size_t)24 * 64 * 2048 * 2;
    unsigned short* ao    = (unsigned short*)w;

    // fused converts (Q weight rows pre-scaled by 0.125*log2e)
    {
        const int total = (BN * C + C3 * C + C * C) / 4;
        cvt_all<<<total / 256, 256, 0, stream>>>(x, qkv_w, proj_w, xb, wqkv, wproj);
    }

    // qkv GEMM with split epilogue: Q,K -> qk[.][1536]; V -> vT (tiled layout)
    gemm_bt<2, 128, 4><<<dim3(BN / 128, C3 / 128), 256, 0, stream>>>(
        xb, wqkv, qk, vT, nullptr, nullptr, BN, C3, C);

    attn_fwd<<<dim3(768), 256, 0, stream>>>(qk, vT, mask, ao);

    // out = ao @ proj_w^T + b (fp32), 64x64 tiles -> 768 blocks (3/CU balanced)
    gemm_bt<1, 64, 2><<<dim3(BN / 64, C / 64), 256, 0, stream>>>(
        ao, wproj, nullptr, nullptr, out, proj_b, BN, C, C);
}

// Round 12
// 94.166 us; speedup vs baseline: 1.8026x; 1.1020x over previous
//
#include <hip/hip_runtime.h>
#include <hip/hip_bf16.h>
#include <math.h>
#include <cstdint>
#include <cstddef>

typedef __bf16 bf16x8 __attribute__((ext_vector_type(8)));
typedef __bf16 bf16x4 __attribute__((ext_vector_type(4)));
typedef short  s16x4  __attribute__((ext_vector_type(4)));
typedef float  f32x4  __attribute__((ext_vector_type(4)));

#define GLOAD16(g, l) __builtin_amdgcn_global_load_lds( \
    (const __attribute__((address_space(1))) void*)(g),  \
    (__attribute__((address_space(3))) void*)(l), 16, 0, 0)

__device__ __forceinline__ unsigned short f2bf(float f) {
    union { float f; unsigned u; } v; v.f = f;
    unsigned u = v.u;
    u += 0x7fffu + ((u >> 16) & 1u);          // round-to-nearest-even
    return (unsigned short)(u >> 16);
}

__device__ __forceinline__ unsigned pack_bf16x2(float a, float b) {
    __hip_bfloat162 h = __float22bfloat162_rn(make_float2(a, b));
    return *reinterpret_cast<unsigned*>(&h);   // v_cvt_pk_bf16_f32
}

// 16x16x16 bf16 MFMA (2-VGPR A/B operands, kv as k-dim)
__device__ __forceinline__ f32x4 mfma16(bf16x4 a, bf16x4 b, f32x4 c) {
#if __has_builtin(__builtin_amdgcn_mfma_f32_16x16x16_bf16)
    return __builtin_amdgcn_mfma_f32_16x16x16_bf16(a, b, c, 0, 0, 0);
#elif __has_builtin(__builtin_amdgcn_mfma_f32_16x16x16bf16_1k)
    return __builtin_amdgcn_mfma_f32_16x16x16bf16_1k(
        __builtin_bit_cast(s16x4, a), __builtin_bit_cast(s16x4, b), c, 0, 0, 0);
#else
    asm volatile("v_mfma_f32_16x16x16_bf16 %0, %1, %2, %0"
                 : "+v"(c) : "v"(a), "v"(b));
    return c;
#endif
}

// ---- fused fp32 -> bf16 converts (x | qkv_w [Q rows pre-scaled] | proj_w) ----
__global__ __launch_bounds__(256) void cvt_all(
    const float* __restrict__ x,
    const float* __restrict__ qkvw,
    const float* __restrict__ projw,
    unsigned short* __restrict__ xb,
    unsigned short* __restrict__ wqkv,
    unsigned short* __restrict__ wproj)
{
    const int N1 = 4096 * 768;          // x
    const int N2 = 2304 * 768;          // qkv_w
    const int SC = 768 * 768;           // Q rows of qkv_w (scaled)
    const float C2 = 0.18033688011112042f;   // 0.125 * log2(e)
    int i = ((int)blockIdx.x * 256 + (int)threadIdx.x) * 4;

    const float* src;
    unsigned short* dst;
    int j;
    bool sc = false;
    if (i < N1)           { src = x;     dst = xb;    j = i; }
    else if (i < N1 + N2) { j = i - N1;  src = qkvw;  dst = wqkv;  sc = (j < SC); }
    else                  { j = i - N1 - N2; src = projw; dst = wproj; }

    float4 v = *reinterpret_cast<const float4*>(src + j);
    if (sc) { v.x *= C2; v.y *= C2; v.z *= C2; v.w *= C2; }
    uint2 pk;
    pk.x = pack_bf16x2(v.x, v.y);
    pk.y = pack_bf16x2(v.z, v.w);
    *reinterpret_cast<uint2*>(dst + j) = pk;
}

// -------- bf16 GEMM, C = A * B^T, 2-phase dbuf, T2 XOR-swizzled LDS --------
// MODE 1: fp32 out + bias.
// MODE 2: qkv split — cols <1536 -> bf16 qk[row][1536]; V cols -> vT tiled:
//         vT[bhh][t][w][g][d][j] — the exact LDS image attn stages.
template <int MODE, int MROWS, int NF>
__global__ __launch_bounds__(256) void gemm_bt(
    const unsigned short* __restrict__ A,
    const unsigned short* __restrict__ B,
    unsigned short* __restrict__ Cb,
    unsigned short* __restrict__ Vt,
    float* __restrict__ Cf,
    const float* __restrict__ bias,
    int M, int N, int K)
{
    constexpr int MI = MROWS / 32;
    __shared__ __align__(16) unsigned short Al[2][MROWS * 64];
    __shared__ __align__(16) unsigned short Bl[2][NF * 32 * 64];
    const int bm   = blockIdx.x * MROWS;
    const int bn   = blockIdx.y * (NF * 32);
    const int tid  = (int)threadIdx.x;
    const int wave = tid >> 6;
    const int lane = tid & 63;
    const int wr   = wave >> 1;
    const int wc   = wave & 1;
    const int q    = lane & 15;
    const int g4   = (lane >> 4) * 4;
    const int swz  = (q & 7) << 3;       // read-side XOR (elems)

    f32x4 acc[MI][NF] = {};

    const int srow = lane >> 3;
    const int scol = ((lane & 7) ^ srow) * 8;   // inverse-swizzled source col

    auto stage = [&](int buf, int k0) {
#pragma unroll
        for (int i = 0; i < MI; ++i) {
            const int chunk = wave * MI + i;
            GLOAD16(A + (size_t)(bm + chunk * 8 + srow) * K + (k0 + scol),
                    &Al[buf][chunk * 512]);
        }
#pragma unroll
        for (int i = 0; i < NF; ++i) {
            const int chunk = wave * NF + i;
            GLOAD16(B + (size_t)(bn + chunk * 8 + srow) * K + (k0 + scol),
                    &Bl[buf][chunk * 512]);
        }
    };

    stage(0, 0);
    __syncthreads();

    const int nt = K / 64;
    int buf = 0;
    for (int t = 0; t < nt; ++t) {
        if (t + 1 < nt) stage(buf ^ 1, (t + 1) * 64);   // issue before compute
#pragma unroll
        for (int kk = 0; kk < 2; ++kk) {
            const int ko = kk * 32 + (lane >> 4) * 8;
            bf16x8 af[MI], bf[NF];
#pragma unroll
            for (int mi = 0; mi < MI; ++mi)
                af[mi] = *(const bf16x8*)&Al[buf][(wr * (MROWS / 2) + mi * 16 + q) * 64
                                                  + (ko ^ swz)];
#pragma unroll
            for (int ni = 0; ni < NF; ++ni)
                bf[ni] = *(const bf16x8*)&Bl[buf][(wc * 16 * NF + ni * 16 + q) * 64
                                                  + (ko ^ swz)];
#pragma unroll
            for (int mi = 0; mi < MI; ++mi)
#pragma unroll
                for (int ni = 0; ni < NF; ++ni)
                    acc[mi][ni] = __builtin_amdgcn_mfma_f32_16x16x32_bf16(
                        af[mi], bf[ni], acc[mi][ni], 0, 0, 0);
        }
        __syncthreads();             // drains this iter's stage + closes reads
        buf ^= 1;
    }

#pragma unroll
    for (int mi = 0; mi < MI; ++mi) {
        const int row0 = bm + wr * (MROWS / 2) + mi * 16 + g4;
        if constexpr (MODE == 1) {
#pragma unroll
            for (int ni = 0; ni < NF; ++ni) {
                const int col = bn + wc * 16 * NF + ni * 16 + q;
#pragma unroll
                for (int r = 0; r < 4; ++r)
                    Cf[(size_t)(row0 + r) * N + col] = acc[mi][ni][r] + bias[col];
            }
        } else {
            if (bn < 1536) {
#pragma unroll
                for (int ni = 0; ni < NF; ++ni) {
                    const int col = bn + wc * 16 * NF + ni * 16 + q;
#pragma unroll
                    for (int r = 0; r < 4; ++r)
                        Cb[(size_t)(row0 + r) * 1536 + col] = f2bf(acc[mi][ni][r]);
                }
            } else {
                const int bb  = row0 >> 11;
                const int np  = row0 & 2047;           // np % 4 == 0
                const int tt  = np >> 6;
                const int wv  = (np >> 4) & 3;
                const int gg  = (np >> 2) & 3;
#pragma unroll
                for (int ni = 0; ni < NF; ++ni) {
                    const int vcol = bn + wc * 16 * NF + ni * 16 + q - 1536;
                    const int hv = vcol >> 6, d = vcol & 63;
                    const size_t idx =
                        ((size_t)((bb * 12 + hv) * 32 + tt) * 4 + wv) * 1024
                        + gg * 256 + d * 4;
                    uint2 w;
                    w.x = pack_bf16x2(acc[mi][ni][0], acc[mi][ni][1]);
                    w.y = pack_bf16x2(acc[mi][ni][2], acc[mi][ni][3]);
                    *reinterpret_cast<uint2*>(&Vt[idx]) = w;   // coalesced
                }
            }
        }
    }
}

// --- fused flash attention: kv-split waves, wave-private LDS, 0 barriers ---
// (R10 structure verbatim — benched 49.7 us, 0 bank conflicts, no spills)
// qk: [B*N][1536] bf16 (Q pre-scaled); vT tiled [bhh][t][w][g][d][j]
// 1D grid 768, XCD-chunked: xcd = bid&7 owns bh in {3*xcd..3*xcd+2}.
__global__ __launch_bounds__(256, 3) void attn_fwd(
    const unsigned short* __restrict__ qk,
    const unsigned short* __restrict__ vT,
    const int* __restrict__ mask,
    unsigned short* __restrict__ out)
{
    const int NN = 2048, H = 12;
    const int bid = (int)blockIdx.x;
    const int bhh = (bid & 7) * 3 + ((bid >> 3) >> 5);   // 0..23
    const int qt  = (bid >> 3) & 31;
    const int b   = bhh / H, h = bhh % H;
    const int q0  = qt * 64;
    const int tid = (int)threadIdx.x, wave = tid >> 6, lane = tid & 63;
    const int g   = lane >> 4;
    const int q   = lane & 15;
    const int swz = (q & 7) << 3;

    // LDS: K 2x4096 | V 2x4096 | lbuf 256 f32  => 33792 B
    __shared__ __align__(16) unsigned short LDS[16896];
    unsigned short* Kl0 = LDS;           // [buf][kv 64][d 64]
    unsigned short* Vl0 = LDS + 8192;    // [buf][wave][g 4][d 64][j 4]

    // wave-local mask vote: all 2048 entries nonzero?
    bool allone;
    {
        const int* mrow = mask + b * NN + lane * 32;
        unsigned mv = 0xFFFFFFFFu;
#pragma unroll
        for (int i = 0; i < 8; ++i) {
            int4 m = *reinterpret_cast<const int4*>(mrow + i * 4);
            mv = min(mv, min(min((unsigned)m.x, (unsigned)m.y),
                             min((unsigned)m.z, (unsigned)m.w)));
        }
        allone = __all(mv != 0u);
    }

    // Q B-fragments for all 4 q-tiles: B[k=d=kk*32+g*8+j][col=q0+16qt+q]
    bf16x8 qf[2][4];
#pragma unroll
    for (int kk = 0; kk < 2; ++kk)
#pragma unroll
        for (int qtl = 0; qtl < 4; ++qtl)
            qf[kk][qtl] = *reinterpret_cast<const bf16x8*>(
                &qk[(size_t)(b * NN + q0 + 16 * qtl + q) * 1536 + h * 64 + kk * 32 + g * 8]);

    // K staging (own 16 kv rows; linear LDS dest, inverse-swizzled source col)
    const char* kg0 = (const char*)(qk + (size_t)(b * NN + wave * 16 + (lane >> 3)) * 1536
                                    + 768 + h * 64 + ((lane & 7) ^ (lane >> 3)) * 8);
    const char* kg1 = kg0 + (size_t)8 * 1536 * 2;
    // V staging: vT tiled layout — perfectly linear, lane*16B
    const unsigned short* vgp = vT + ((size_t)bhh * 32 * 4 + wave) * 1024 + lane * 8;

    auto stageK = [&](int buf) {
        GLOAD16(kg0, &Kl0[buf * 4096 + wave * 1024]);
        GLOAD16(kg1, &Kl0[buf * 4096 + wave * 1024 + 512]);
        kg0 += (size_t)64 * 1536 * 2;
        kg1 += (size_t)64 * 1536 * 2;
    };
    auto stageV = [&](int buf) {
        GLOAD16(vgp,       &Vl0[buf * 4096 + wave * 1024]);
        GLOAD16(vgp + 512, &Vl0[buf * 4096 + wave * 1024 + 512]);
        vgp += 4096;                     // next kv tile
    };

    f32x4 oacc[4][4] = {};          // [ct: d-tile][qtl: q-tile]
    float l[4] = {0.f, 0.f, 0.f, 0.f};

    stageK(0); stageV(0);           // 4 loads in flight (no barrier needed)

    int cur = 0;
    for (int it = 0; it < 32; ++it) {
        if (it < 31) { stageK(cur ^ 1); stageV(cur ^ 1); }

        // K(it) resident; V(it) + next iter's 4 stay in flight
        if (it < 31) asm volatile("s_waitcnt vmcnt(6)" ::: "memory");
        else         asm volatile("s_waitcnt vmcnt(2)" ::: "memory");

        // S^T[own 16 kv][64 q] = K_own * Q^T  (exp2 units; scale pre-folded)
        f32x4 s[4] = {};
        __builtin_amdgcn_s_setprio(1);
#pragma unroll
        for (int kk = 0; kk < 2; ++kk) {
            bf16x8 kf = *(const bf16x8*)&Kl0[cur * 4096 + (16 * wave + q) * 64
                                             + ((kk * 32 + g * 8) ^ swz)];
#pragma unroll
            for (int qtl = 0; qtl < 4; ++qtl)
                s[qtl] = __builtin_amdgcn_mfma_f32_16x16x32_bf16(kf, qf[kk][qtl], s[qtl], 0, 0, 0);
        }
        __builtin_amdgcn_s_setprio(0);

        if (!allone) {               // cold path: mask by absolute kv
            int4 mr = *reinterpret_cast<const int4*>(
                &mask[b * NN + it * 64 + 16 * wave + 4 * g]);
#pragma unroll
            for (int qtl = 0; qtl < 4; ++qtl) {
                if (mr.x == 0) s[qtl][0] = -INFINITY;
                if (mr.y == 0) s[qtl][1] = -INFINITY;
                if (mr.z == 0) s[qtl][2] = -INFINITY;
                if (mr.w == 0) s[qtl][3] = -INFINITY;
            }
        }

        // p = exp2(s); per-lane l partials (reduced at epilogue); pack to bf16
        bf16x4 pb[4];
#pragma unroll
        for (int qtl = 0; qtl < 4; ++qtl) {
            float p0 = __builtin_amdgcn_exp2f(s[qtl][0]);
            float p1 = __builtin_amdgcn_exp2f(s[qtl][1]);
            float p2 = __builtin_amdgcn_exp2f(s[qtl][2]);
            float p3 = __builtin_amdgcn_exp2f(s[qtl][3]);
            l[qtl] += (p0 + p1) + (p2 + p3);
            uint2 t;
            t.x = pack_bf16x2(p0, p1);
            t.y = pack_bf16x2(p2, p3);
            pb[qtl] = __builtin_bit_cast(bf16x4, t);
        }

        // V(it) resident; next iter's 4 remain in flight
        if (it < 31) asm volatile("s_waitcnt vmcnt(4)" ::: "memory");
        else         asm volatile("s_waitcnt vmcnt(0)" ::: "memory");

        // O^T[64 d][64 q] partial += V_own^T * P^T  (P in registers)
        __builtin_amdgcn_s_setprio(1);
#pragma unroll
        for (int ct = 0; ct < 4; ++ct) {
            // [g][d][j] layout: banks 2q,2q+1 -> conflict-free
            bf16x4 va = *(const bf16x4*)&Vl0[cur * 4096 + wave * 1024
                                             + g * 256 + (16 * ct + q) * 4];
#pragma unroll
            for (int qtl = 0; qtl < 4; ++qtl)
                oacc[ct][qtl] = mfma16(va, pb[qtl], oacc[ct][qtl]);
        }
        __builtin_amdgcn_s_setprio(0);

        cur ^= 1;
    }

    __syncthreads();   // all waves done with K/V LDS before epilogue overlay

    // ---- epilogue: reduce l (over g, then waves) and O (over waves) ----
#pragma unroll
    for (int qtl = 0; qtl < 4; ++qtl) {
        l[qtl] += __shfl_xor(l[qtl], 16);
        l[qtl] += __shfl_xor(l[qtl], 32);
    }
    float* lb = (float*)&LDS[16384];
    float* fb = (float*)&LDS[0];
    if (g == 0) {
#pragma unroll
        for (int qtl = 0; qtl < 4; ++qtl) lb[wave * 64 + qtl * 16 + q] = l[qtl];
    }
    // round 1: waves 1,3 dump partials (16 KB each)
    if (wave & 1) {
        float* dst = fb + (wave >> 1) * 4096;
#pragma unroll
        for (int ct = 0; ct < 4; ++ct)
#pragma unroll
            for (int qtl = 0; qtl < 4; ++qtl)
                *reinterpret_cast<f32x4*>(&dst[(ct * 4 + qtl) * 256 + lane * 4]) = oacc[ct][qtl];
    }
    __syncthreads();
    if (!(wave & 1)) {
        float* srcp = fb + (wave >> 1) * 4096;
#pragma unroll
        for (int ct = 0; ct < 4; ++ct)
#pragma unroll
            for (int qtl = 0; qtl < 4; ++qtl)
                oacc[ct][qtl] += *reinterpret_cast<f32x4*>(&srcp[(ct * 4 + qtl) * 256 + lane * 4]);
    }
    __syncthreads();
    // round 2: wave 2 dumps merged partial
    if (wave == 2) {
#pragma unroll
        for (int ct = 0; ct < 4; ++ct)
#pragma unroll
            for (int qtl = 0; qtl < 4; ++qtl)
                *reinterpret_cast<f32x4*>(&fb[(ct * 4 + qtl) * 256 + lane * 4]) = oacc[ct][qtl];
    }
    __syncthreads();
    if (wave == 0) {
        float inv[4];
#pragma unroll
        for (int qtl = 0; qtl < 4; ++qtl)
            inv[qtl] = 1.0f / (lb[qtl * 16 + q] + lb[64 + qtl * 16 + q]
                              + lb[128 + qtl * 16 + q] + lb[192 + qtl * 16 + q]);
#pragma unroll
        for (int ct = 0; ct < 4; ++ct)
#pragma unroll
            for (int qtl = 0; qtl < 4; ++qtl) {
                f32x4 o = oacc[ct][qtl]
                        + *reinterpret_cast<f32x4*>(&fb[(ct * 4 + qtl) * 256 + lane * 4]);
                uint2 ow;
                ow.x = pack_bf16x2(o[0] * inv[qtl], o[1] * inv[qtl]);
                ow.y = pack_bf16x2(o[2] * inv[qtl], o[3] * inv[qtl]);
                *reinterpret_cast<uint2*>(
                    &out[(size_t)(b * NN + q0 + 16 * qtl + q) * 768 + h * 64 + 16 * ct + 4 * g]) = ow;
            }
    }
}

// ---------------- host launch ----------------
extern "C" void kernel_launch(void* const* d_in, const int* in_sizes, int n_in,
                              void* d_out, int out_size, void* d_ws, size_t ws_size,
                              hipStream_t stream)
{
    const float* x      = (const float*)d_in[0];
    const int*   mask   = (const int*)d_in[1];
    const float* qkv_w  = (const float*)d_in[2];
    const float* proj_w = (const float*)d_in[3];
    const float* proj_b = (const float*)d_in[4];
    float* out = (float*)d_out;

    const int BN = 2 * 2048;
    const int C  = 768;
    const int C3 = 2304;

    char* w = (char*)d_ws;
    unsigned short* xb    = (unsigned short*)w; w += (size_t)BN * C    * 2;
    unsigned short* wqkv  = (unsigned short*)w; w += (size_t)C3 * C    * 2;
    unsigned short* wproj = (unsigned short*)w; w += (size_t)C  * C    * 2;
    unsigned short* qk    = (unsigned short*)w; w += (size_t)BN * 1536 * 2;
    unsigned short* vT    = (unsigned short*)w; w += (size_t)24 * 64 * 2048 * 2;
    unsigned short* ao    = (unsigned short*)w;

    // fused converts (Q weight rows pre-scaled by 0.125*log2e)
    {
        const int total = (BN * C + C3 * C + C * C) / 4;
        cvt_all<<<total / 256, 256, 0, stream>>>(x, qkv_w, proj_w, xb, wqkv, wproj);
    }

    // qkv GEMM with split epilogue: Q,K -> qk[.][1536]; V -> vT (tiled layout)
    gemm_bt<2, 128, 4><<<dim3(BN / 128, C3 / 128), 256, 0, stream>>>(
        xb, wqkv, qk, vT, nullptr, nullptr, BN, C3, C);

    attn_fwd<<<dim3(768), 256, 0, stream>>>(qk, vT, mask, ao);

    // out = ao @ proj_w^T + b (fp32), 64x64 tiles -> 768 blocks (3/CU balanced)
    gemm_bt<1, 64, 2><<<dim3(BN / 64, C / 64), 256, 0, stream>>>(
        ao, wproj, nullptr, nullptr, out, proj_b, BN, C, C);
}